// Round 1
// baseline (1125.267 us; speedup 1.0000x reference)
//
#include <hip/hip_runtime.h>

constexpr int Bn = 4;
constexpr int Hn = 64;
constexpr int Wn = 64;
constexpr int LL = Hn * Wn;     // 4096
constexpr int DM = 128;
constexpr int DI = 256;
constexpr int Nn = 16;
constexpr int Rn = 8;
constexpr int Kn = 4;

// ---------- helpers ----------
__device__ __forceinline__ float bf2f(unsigned short s) {
    return __uint_as_float(((unsigned int)s) << 16);
}
__device__ __forceinline__ unsigned short f2bf(float f) {
    unsigned int u = __float_as_uint(f);
    u += 0x7FFFu + ((u >> 16) & 1u);   // RNE
    return (unsigned short)(u >> 16);
}
__device__ __forceinline__ float softplus_f(float x) {
    if (x > 20.f) return x;
    return __logf(1.f + __expf(x));
}

// ---------- kernel 0: transpose x_proj_weight (K,40,DI) -> wT (K,DI,40) ----------
__global__ __launch_bounds__(256) void k_wt(const float* __restrict__ xpw, float* __restrict__ wT) {
    int i = blockIdx.x * 256 + threadIdx.x;
    if (i >= Kn * 40 * DI) return;
    int d = i % DI;
    int c = (i / DI) % 40;
    int k = i / (40 * DI);
    wT[(k * DI + d) * 40 + c] = xpw[i];
}

// ---------- kernel 1: in_proj GEMM: out[b,d,l] = sum_c x[b,l,c]*W[d,c] ----------
// grid 1024 = 64 ltiles * 4 dtiles * 4 b ; block 256
__global__ __launch_bounds__(256) void k_inproj(const float* __restrict__ x,
                                                const float* __restrict__ wp,
                                                float* __restrict__ out) {
    __shared__ float sx[64][68];  // [c][l]
    __shared__ float sw[64][68];  // [c][d]
    int bid = blockIdx.x;
    int lt = bid & 63;
    int dt = (bid >> 6) & 3;
    int b  = bid >> 8;
    int l0 = lt * 64, d0 = dt * 64;
    int tid = threadIdx.x;
    int tx = tid & 15, ty = tid >> 4;
    float acc[4][4] = {};
    for (int kc0 = 0; kc0 < DM; kc0 += 64) {
        #pragma unroll
        for (int i = 0; i < 4; ++i) {
            int idx = tid + i * 256;            // 1024 float4 per tile
            int row = idx >> 4, c4 = idx & 15;
            float4 v = *(const float4*)(x + ((size_t)b * LL + l0 + row) * DM + kc0 + c4 * 4);
            sx[c4 * 4 + 0][row] = v.x; sx[c4 * 4 + 1][row] = v.y;
            sx[c4 * 4 + 2][row] = v.z; sx[c4 * 4 + 3][row] = v.w;
            float4 u = *(const float4*)(wp + (size_t)(d0 + row) * DM + kc0 + c4 * 4);
            sw[c4 * 4 + 0][row] = u.x; sw[c4 * 4 + 1][row] = u.y;
            sw[c4 * 4 + 2][row] = u.z; sw[c4 * 4 + 3][row] = u.w;
        }
        __syncthreads();
        #pragma unroll 8
        for (int kc = 0; kc < 64; ++kc) {
            float4 xv = *(const float4*)&sx[kc][tx * 4];
            float4 wv = *(const float4*)&sw[kc][ty * 4];
            float xa[4] = {xv.x, xv.y, xv.z, xv.w};
            float wa[4] = {wv.x, wv.y, wv.z, wv.w};
            #pragma unroll
            for (int i = 0; i < 4; ++i)
                #pragma unroll
                for (int j = 0; j < 4; ++j)
                    acc[i][j] += wa[i] * xa[j];
        }
        __syncthreads();
    }
    #pragma unroll
    for (int i = 0; i < 4; ++i) {
        float4 v = {acc[i][0], acc[i][1], acc[i][2], acc[i][3]};
        *(float4*)(out + ((size_t)b * DI + d0 + ty * 4 + i) * LL + l0 + tx * 4) = v;
    }
}

// ---------- kernel 2: depthwise 3x3 conv + bias + SiLU (NCHW) ----------
// grid 16384 = 4b * 256d * 16 htiles ; block 256 = 64w * 4h
__global__ __launch_bounds__(256) void k_conv(const float* __restrict__ xin,
                                              const float* __restrict__ cw,
                                              const float* __restrict__ cb,
                                              float* __restrict__ xout) {
    int bid = blockIdx.x;
    int ht = bid & 15;
    int d  = (bid >> 4) & 255;
    int b  = bid >> 12;
    int tid = threadIdx.x;
    int wc = tid & 63, hh = tid >> 6;
    int h = ht * 4 + hh;
    const float* base = xin + ((size_t)b * DI + d) * LL;
    float wgt[9];
    #pragma unroll
    for (int i = 0; i < 9; ++i) wgt[i] = cw[d * 9 + i];
    float acc = cb[d];
    #pragma unroll
    for (int di = 0; di < 3; ++di) {
        int hy = h + di - 1;
        if (hy < 0 || hy >= Hn) continue;
        #pragma unroll
        for (int dj = 0; dj < 3; ++dj) {
            int wx = wc + dj - 1;
            if (wx < 0 || wx >= Wn) continue;
            acc += wgt[di * 3 + dj] * base[hy * Wn + wx];
        }
    }
    float sig = 1.f / (1.f + __expf(-acc));
    xout[((size_t)b * DI + d) * LL + h * Wn + wc] = acc * sig;
}

// ---------- kernel 3: x_dbl[b,k,c,l] = sum_d wT[k,d,c]*xs[b,k,d,l] ----------
// grid 256 = 4b*4k*16 ltiles(256) ; block 256 (thread per l)
__global__ __launch_bounds__(256) void k_xdbl(const float* __restrict__ xc,
                                              const float* __restrict__ wT,
                                              float* __restrict__ xdbl) {
    __shared__ float sxs[32][260];
    int bid = blockIdx.x;
    int lt = bid & 15;
    int k  = (bid >> 4) & 3;
    int b  = bid >> 6;
    int l0 = lt * 256;
    int tid = threadIdx.x;
    float acc[40] = {};
    const float* wbase = wT + k * DI * 40;
    const float* xb = xc + (size_t)b * DI * LL;
    for (int d0 = 0; d0 < DI; d0 += 32) {
        if (k == 0) {
            #pragma unroll
            for (int i = 0; i < 8; ++i) {
                int idx = tid + i * 256;         // 2048 float4
                int dd = idx >> 6, c4 = idx & 63;
                float4 v = *(const float4*)(xb + (size_t)(d0 + dd) * LL + l0 + c4 * 4);
                *(float4*)&sxs[dd][c4 * 4] = v;
            }
        } else if (k == 2) {
            #pragma unroll
            for (int i = 0; i < 8; ++i) {
                int idx = tid + i * 256;
                int dd = idx >> 6, c4 = idx & 63;
                float4 v = *(const float4*)(xb + (size_t)(d0 + dd) * LL + (LL - 4 - l0 - c4 * 4));
                float4 rv = {v.w, v.z, v.y, v.x};
                *(float4*)&sxs[dd][c4 * 4] = rv;
            }
        } else {
            for (int i = 0; i < 32; ++i) {
                int idx = tid + i * 256;         // 8192 scalars
                int dd = idx >> 8, ll = idx & 255;
                int lq = (k == 1) ? (l0 + ll) : (LL - 1 - (l0 + ll));
                int pos = ((lq & 63) << 6) | (lq >> 6);
                sxs[dd][ll] = xb[(size_t)(d0 + dd) * LL + pos];
            }
        }
        __syncthreads();
        #pragma unroll 4
        for (int dd = 0; dd < 32; ++dd) {
            float xv = sxs[dd][tid];
            const float* wr = wbase + (d0 + dd) * 40;
            #pragma unroll
            for (int c = 0; c < 40; ++c) acc[c] += wr[c] * xv;
        }
        __syncthreads();
    }
    float* ob = xdbl + (size_t)(b * Kn + k) * 40 * LL + l0 + tid;
    #pragma unroll
    for (int c = 0; c < 40; ++c) ob[(size_t)c * LL] = acc[c];
}

// ---------- kernel 4: delta[b,k,d,l] = softplus(sum_r dtw[k,d,r]*dts[b,k,r,l] + bias) -> bf16 ----------
// grid 16384 = 4b*4k*256d*4 lchunks ; block 256 (4 l per thread)
__global__ __launch_bounds__(256) void k_delta(const float* __restrict__ xdbl,
                                               const float* __restrict__ dtw,
                                               const float* __restrict__ dtb,
                                               unsigned short* __restrict__ delta) {
    int bid = blockIdx.x;
    int lc = bid & 3;
    int d  = (bid >> 2) & 255;
    int k  = (bid >> 10) & 3;
    int b  = bid >> 12;
    int tid = threadIdx.x;
    int l = lc * 1024 + tid * 4;
    const float* db = xdbl + (size_t)(b * Kn + k) * 40 * LL;
    float ax = 0, ay = 0, az = 0, aw = 0;
    #pragma unroll
    for (int r = 0; r < Rn; ++r) {
        float wv = dtw[(k * DI + d) * Rn + r];
        float4 v = *(const float4*)(db + (size_t)r * LL + l);
        ax += wv * v.x; ay += wv * v.y; az += wv * v.z; aw += wv * v.w;
    }
    float bias = dtb[k * DI + d];
    ushort4 st;
    st.x = f2bf(softplus_f(ax + bias));
    st.y = f2bf(softplus_f(ay + bias));
    st.z = f2bf(softplus_f(az + bias));
    st.w = f2bf(softplus_f(aw + bias));
    *(ushort4*)(delta + ((size_t)(b * Kn + k) * DI + d) * LL + l) = st;
}

// ---------- kernel 5: selective scan ----------
template <int KK>
__device__ __forceinline__ void load_u8(const float* __restrict__ urow, int t, float u[8]) {
    if constexpr (KK == 0) {
        float4 a = *(const float4*)(urow + t);
        float4 b = *(const float4*)(urow + t + 4);
        u[0] = a.x; u[1] = a.y; u[2] = a.z; u[3] = a.w;
        u[4] = b.x; u[5] = b.y; u[6] = b.z; u[7] = b.w;
    } else if constexpr (KK == 2) {
        float4 a = *(const float4*)(urow + (LL - 4 - t));
        float4 b = *(const float4*)(urow + (LL - 8 - t));
        u[0] = a.w; u[1] = a.z; u[2] = a.y; u[3] = a.x;
        u[4] = b.w; u[5] = b.z; u[6] = b.y; u[7] = b.x;
    } else if constexpr (KK == 1) {
        int base = t >> 6, wr = t & 63;
        #pragma unroll
        for (int j = 0; j < 8; ++j) u[j] = urow[((wr + j) << 6) | base];
    } else {
        int tq = LL - 1 - t;
        int base = tq >> 6, wr = tq & 63;
        #pragma unroll
        for (int j = 0; j < 8; ++j) u[j] = urow[((wr - j) << 6) | base];
    }
}

template <int KK>
__device__ __forceinline__ void scan_loop(const float* __restrict__ urow,
                                          const float* __restrict__ Brow,
                                          const float* __restrict__ Crow,
                                          const unsigned short* __restrict__ drow,
                                          float Acoef, float Dv, int n, float* __restrict__ yb) {
    float h = 0.f;
    float4 nB0 = *(const float4*)(Brow + 0), nB1 = *(const float4*)(Brow + 4);
    float4 nC0 = *(const float4*)(Crow + 0), nC1 = *(const float4*)(Crow + 4);
    ushort4 nE0 = *(const ushort4*)(drow + 0), nE1 = *(const ushort4*)(drow + 4);
    float nu[8];
    load_u8<KK>(urow, 0, nu);
    for (int t = 0; t < LL; t += 8) {
        float4 B0 = nB0, B1 = nB1, C0 = nC0, C1 = nC1;
        ushort4 E0 = nE0, E1 = nE1;
        float u[8];
        #pragma unroll
        for (int j = 0; j < 8; ++j) u[j] = nu[j];
        int t2 = (t + 8 < LL) ? (t + 8) : 0;   // prefetch next iter (dummy-safe at end)
        nB0 = *(const float4*)(Brow + t2); nB1 = *(const float4*)(Brow + t2 + 4);
        nC0 = *(const float4*)(Crow + t2); nC1 = *(const float4*)(Crow + t2 + 4);
        nE0 = *(const ushort4*)(drow + t2); nE1 = *(const ushort4*)(drow + t2 + 4);
        load_u8<KK>(urow, t2, nu);
        float Ba[8] = {B0.x, B0.y, B0.z, B0.w, B1.x, B1.y, B1.z, B1.w};
        float Ca[8] = {C0.x, C0.y, C0.z, C0.w, C1.x, C1.y, C1.z, C1.w};
        unsigned short Ea[8] = {E0.x, E0.y, E0.z, E0.w, E1.x, E1.y, E1.z, E1.w};
        #pragma unroll
        for (int j = 0; j < 8; ++j) {
            float de = bf2f(Ea[j]);
            float a = __expf(de * Acoef);
            h = a * h + (de * u[j]) * Ba[j];
            float p = h * Ca[j];
            p += __shfl_xor(p, 1);
            p += __shfl_xor(p, 2);
            p += __shfl_xor(p, 4);
            p += __shfl_xor(p, 8);
            int pos;
            if constexpr (KK == 0)      pos = t + j;
            else if constexpr (KK == 2) pos = LL - 1 - t - j;
            else if constexpr (KK == 1) pos = (((t & 63) + j) << 6) | (t >> 6);
            else { int tq = LL - 1 - t; pos = (((tq & 63) - j) << 6) | (tq >> 6); }
            if (n == 0) atomicAdd(yb + (size_t)pos * DI, p + Dv * u[j]);
        }
    }
}

// grid 256 = 4b*4k*16 dblks ; block 256 ; lane=(d mod 4, n)
__global__ __launch_bounds__(256) void k_scan(const float* __restrict__ xc,
                                              const float* __restrict__ xdbl,
                                              const unsigned short* __restrict__ delta,
                                              const float* __restrict__ A_logs,
                                              const float* __restrict__ Ds,
                                              float* __restrict__ y) {
    int bid = blockIdx.x;
    int dblk = bid & 15;
    int k = (bid >> 4) & 3;
    int b = bid >> 6;
    int tid = threadIdx.x;
    int wave = tid >> 6, lane = tid & 63;
    int g = lane >> 4, n = lane & 15;
    int d = dblk * 16 + wave * 4 + g;
    int kd = k * DI + d;
    float Acoef = -__expf(A_logs[kd * Nn + n]);
    float Dv = Ds[kd];
    const float* Brow = xdbl + ((size_t)(b * Kn + k) * 40 + 8 + n) * LL;
    const float* Crow = Brow + (size_t)16 * LL;
    const unsigned short* drow = delta + ((size_t)(b * Kn + k) * DI + d) * LL;
    const float* urow = xc + ((size_t)b * DI + d) * LL;
    float* yb = y + (size_t)b * LL * DI + d;
    if (k == 0)      scan_loop<0>(urow, Brow, Crow, drow, Acoef, Dv, n, yb);
    else if (k == 1) scan_loop<1>(urow, Brow, Crow, drow, Acoef, Dv, n, yb);
    else if (k == 2) scan_loop<2>(urow, Brow, Crow, drow, Acoef, Dv, n, yb);
    else             scan_loop<3>(urow, Brow, Crow, drow, Acoef, Dv, n, yb);
}

// ---------- kernel 6: LayerNorm over last dim (in-place on d_out) ----------
// grid 16384 rows ; block 256
__global__ __launch_bounds__(256) void k_ln(float* __restrict__ y,
                                            const float* __restrict__ gamma,
                                            const float* __restrict__ beta) {
    __shared__ float s1[4], s2[4];
    int r = blockIdx.x;
    int tid = threadIdx.x;
    float v = y[(size_t)r * DI + tid];
    float a = v, bsq = v * v;
    #pragma unroll
    for (int off = 32; off; off >>= 1) {
        a += __shfl_xor(a, off);
        bsq += __shfl_xor(bsq, off);
    }
    if ((tid & 63) == 0) { s1[tid >> 6] = a; s2[tid >> 6] = bsq; }
    __syncthreads();
    float S1 = s1[0] + s1[1] + s1[2] + s1[3];
    float S2 = s2[0] + s2[1] + s2[2] + s2[3];
    float mu = S1 * (1.f / 256.f);
    float var = S2 * (1.f / 256.f) - mu * mu;
    float rs = rsqrtf(var + 1e-5f);
    y[(size_t)r * DI + tid] = (v - mu) * rs * gamma[tid] + beta[tid];
}

// ---------- launch ----------
extern "C" void kernel_launch(void* const* d_in, const int* in_sizes, int n_in,
                              void* d_out, int out_size, void* d_ws, size_t ws_size,
                              hipStream_t stream) {
    const float* x    = (const float*)d_in[0];
    const float* ipw  = (const float*)d_in[1];
    const float* cw   = (const float*)d_in[2];
    const float* cb   = (const float*)d_in[3];
    const float* xpw  = (const float*)d_in[4];
    const float* dtw  = (const float*)d_in[5];
    const float* dtb  = (const float*)d_in[6];
    const float* alog = (const float*)d_in[7];
    const float* Ds   = (const float*)d_in[8];
    const float* gam  = (const float*)d_in[9];
    const float* bet  = (const float*)d_in[10];

    // ws layout (bytes):
    //   [0, 33554432)          delta (bf16, B*K*D*L)  -- aliases xc_pre (fp32, dead before k_delta)
    //   [33554432, 50331648)   xc (fp32, B*DI*L)
    //   [50331648, 60817408)   x_dbl (fp32, B*K*40*L)
    //   [60817408, 60981248)   wT (fp32, K*DI*40)
    const size_t WS_NEED = 60981248;
    if (ws_size < WS_NEED) return;   // signals as unchanged-poison failure; adjust next round

    char* ws = (char*)d_ws;
    unsigned short* delta = (unsigned short*)(ws + 0);
    float* xc_pre = (float*)(ws + 0);
    float* xc     = (float*)(ws + 33554432);
    float* xdbl   = (float*)(ws + 50331648);
    float* wT     = (float*)(ws + 60817408);
    float* y      = (float*)d_out;

    hipMemsetAsync(d_out, 0, (size_t)out_size * sizeof(float), stream);
    k_wt    <<<160,   256, 0, stream>>>(xpw, wT);
    k_inproj<<<1024,  256, 0, stream>>>(x, ipw, xc_pre);
    k_conv  <<<16384, 256, 0, stream>>>(xc_pre, cw, cb, xc);
    k_xdbl  <<<256,   256, 0, stream>>>(xc, wT, xdbl);
    k_delta <<<16384, 256, 0, stream>>>(xdbl, dtw, dtb, delta);
    k_scan  <<<256,   256, 0, stream>>>(xc, xdbl, delta, alog, Ds, y);
    k_ln    <<<16384, 256, 0, stream>>>(y, gam, bet);
}

// Round 2
// 389.660 us; speedup vs baseline: 2.8878x; 2.8878x over previous
//
#include <hip/hip_runtime.h>

constexpr int Bn = 4;
constexpr int Hn = 64;
constexpr int Wn = 64;
constexpr int LL = Hn * Wn;     // 4096
constexpr int DM = 128;
constexpr int DI = 256;
constexpr int Nn = 16;
constexpr int Rn = 8;
constexpr int Kn = 4;
constexpr int NC = 64;          // chunks per (b,k) scan
constexpr int CHUNK = LL / NC;  // 64

// ---------- helpers ----------
__device__ __forceinline__ float softplus_f(float x) {
    if (x > 20.f) return x;
    return __logf(1.f + __expf(x));
}
// scan-order index t -> image position (row-major h*64+w)
__device__ __forceinline__ int posk(int k, int t) {
    int q = (k >= 2) ? (LL - 1 - t) : t;
    return (k & 1) ? (((q & 63) << 6) | (q >> 6)) : q;
}

// ---------- kernel 1: in_proj GEMM: xp[b,l,d] = sum_c x[b,l,c]*W[d,c] ----------
// grid 1024 = 64 ltiles * 4 dtiles * 4 b ; block 256
__global__ __launch_bounds__(256) void k_inproj(const float* __restrict__ x,
                                                const float* __restrict__ wp,
                                                float* __restrict__ out) {
    __shared__ float sx[64][68];  // [c][l]
    __shared__ float sw[64][68];  // [c][d]
    int bid = blockIdx.x;
    int lt = bid & 63;
    int dt = (bid >> 6) & 3;
    int b  = bid >> 8;
    int l0 = lt * 64, d0 = dt * 64;
    int tid = threadIdx.x;
    int dy = tid & 15;    // d-subtile (fast -> coalesced stores over d)
    int lx = tid >> 4;    // l-subtile
    float acc[4][4] = {}; // [d][l]
    for (int kc0 = 0; kc0 < DM; kc0 += 64) {
        #pragma unroll
        for (int i = 0; i < 4; ++i) {
            int idx = tid + i * 256;
            int row = idx >> 4, c4 = idx & 15;
            float4 v = *(const float4*)(x + ((size_t)b * LL + l0 + row) * DM + kc0 + c4 * 4);
            sx[c4 * 4 + 0][row] = v.x; sx[c4 * 4 + 1][row] = v.y;
            sx[c4 * 4 + 2][row] = v.z; sx[c4 * 4 + 3][row] = v.w;
            float4 u = *(const float4*)(wp + (size_t)(d0 + row) * DM + kc0 + c4 * 4);
            sw[c4 * 4 + 0][row] = u.x; sw[c4 * 4 + 1][row] = u.y;
            sw[c4 * 4 + 2][row] = u.z; sw[c4 * 4 + 3][row] = u.w;
        }
        __syncthreads();
        #pragma unroll 8
        for (int kc = 0; kc < 64; ++kc) {
            float4 xv = *(const float4*)&sx[kc][lx * 4];
            float4 wv = *(const float4*)&sw[kc][dy * 4];
            float xa[4] = {xv.x, xv.y, xv.z, xv.w};
            float wa[4] = {wv.x, wv.y, wv.z, wv.w};
            #pragma unroll
            for (int i = 0; i < 4; ++i)
                #pragma unroll
                for (int j = 0; j < 4; ++j)
                    acc[i][j] += wa[i] * xa[j];
        }
        __syncthreads();
    }
    // store channel-last: out[(b*LL + l)*DI + d], float4 over d
    #pragma unroll
    for (int j = 0; j < 4; ++j) {
        float4 v = {acc[0][j], acc[1][j], acc[2][j], acc[3][j]};
        *(float4*)(out + ((size_t)b * LL + l0 + lx * 4 + j) * DI + d0 + dy * 4) = v;
    }
}

// ---------- kernel 2: depthwise 3x3 conv + bias + SiLU, channel-last ----------
// grid 512 = 4b * 4dblk * 16wblk * 2hhalf ; block 256 = 64 d-lanes * 4 w
__global__ __launch_bounds__(256) void k_conv(const float* __restrict__ xin,
                                              const float* __restrict__ cw,
                                              const float* __restrict__ cb,
                                              float* __restrict__ xout) {
    int bid = blockIdx.x;
    int hh   = bid & 1;
    int wblk = (bid >> 1) & 15;
    int dblk = (bid >> 5) & 3;
    int b    = bid >> 7;
    int tid = threadIdx.x;
    int d = dblk * 64 + (tid & 63);
    int w = wblk * 4 + (tid >> 6);
    const float* inb = xin + (size_t)b * LL * DI + d;
    float* outb = xout + (size_t)b * LL * DI + d;
    float wg[9];
    #pragma unroll
    for (int i = 0; i < 9; ++i) wg[i] = cw[d * 9 + i];
    float bias = cb[d];
    #define LDV(hhh, www) ((((www) >= 0) && ((www) < Wn)) ? inb[(size_t)((hhh) * Wn + (www)) * DI] : 0.f)
    int hs = hh * 32;
    float r0[3], r1[3], r2[3];
    if (hs == 0) { r0[0] = r0[1] = r0[2] = 0.f; }
    else { r0[0] = LDV(hs - 1, w - 1); r0[1] = LDV(hs - 1, w); r0[2] = LDV(hs - 1, w + 1); }
    r1[0] = LDV(hs, w - 1); r1[1] = LDV(hs, w); r1[2] = LDV(hs, w + 1);
    r2[0] = LDV(hs + 1, w - 1); r2[1] = LDV(hs + 1, w); r2[2] = LDV(hs + 1, w + 1);
    for (int h = hs; h < hs + 32; ++h) {
        float acc = bias + wg[0] * r0[0] + wg[1] * r0[1] + wg[2] * r0[2]
                         + wg[3] * r1[0] + wg[4] * r1[1] + wg[5] * r1[2]
                         + wg[6] * r2[0] + wg[7] * r2[1] + wg[8] * r2[2];
        float sig = 1.f / (1.f + __expf(-acc));
        outb[(size_t)(h * Wn + w) * DI] = acc * sig;
        r0[0] = r1[0]; r0[1] = r1[1]; r0[2] = r1[2];
        r1[0] = r2[0]; r1[1] = r2[1]; r1[2] = r2[2];
        if (h + 2 < Hn) { r2[0] = LDV(h + 2, w - 1); r2[1] = LDV(h + 2, w); r2[2] = LDV(h + 2, w + 1); }
        else { r2[0] = r2[1] = r2[2] = 0.f; }
    }
    #undef LDV
}

// ---------- kernel 3: SP[b,k,t][0:40] = x_proj of xs  (dts rows 0..7, B 8..23, C 24..39) ----------
// grid 256 = 4b*4k*16 ltiles(256) ; block 256 (thread per t)
__global__ __launch_bounds__(256) void k_xdbl(const float* __restrict__ xcS,
                                              const float* __restrict__ xpw,
                                              float* __restrict__ SP) {
    __shared__ float sxs[32][260];   // [dd][t]
    __shared__ float swt[40][33];    // [c][dd]
    int bid = blockIdx.x;
    int lt = bid & 15;
    int k  = (bid >> 4) & 3;
    int b  = bid >> 6;
    int l0 = lt * 256;
    int tid = threadIdx.x;
    float acc[40] = {};
    const float* xb = xcS + (size_t)b * LL * DI;
    for (int d0 = 0; d0 < DI; d0 += 32) {
        for (int i = tid; i < 1280; i += 256)
            swt[i >> 5][i & 31] = xpw[(size_t)(k * 40 + (i >> 5)) * DI + d0 + (i & 31)];
        #pragma unroll
        for (int i = 0; i < 8; ++i) {
            int idx = tid + i * 256;
            int row = idx >> 3, cc = idx & 7;
            int pos = posk(k, l0 + row);
            float4 v = *(const float4*)(xb + (size_t)pos * DI + d0 + cc * 4);
            sxs[cc * 4 + 0][row] = v.x; sxs[cc * 4 + 1][row] = v.y;
            sxs[cc * 4 + 2][row] = v.z; sxs[cc * 4 + 3][row] = v.w;
        }
        __syncthreads();
        #pragma unroll 4
        for (int dd = 0; dd < 32; ++dd) {
            float xv = sxs[dd][tid];
            #pragma unroll
            for (int c = 0; c < 40; ++c) acc[c] += swt[c][dd] * xv;
        }
        __syncthreads();
    }
    float* ob = SP + ((size_t)(b * Kn + k) * LL + l0 + tid) * 40;
    #pragma unroll
    for (int c4 = 0; c4 < 10; ++c4) {
        float4 v = {acc[c4 * 4 + 0], acc[c4 * 4 + 1], acc[c4 * 4 + 2], acc[c4 * 4 + 3]};
        *(float4*)(ob + c4 * 4) = v;
    }
}

// ---------- kernel 4: scan phase 1 — per-chunk local scan, emit carries ----------
// grid 1024 = 4b*4k*64c ; block 256 (thread = d)
__global__ __launch_bounds__(256) void k_scan1(const float* __restrict__ xcS,
                                               const float* __restrict__ SP,
                                               const float* __restrict__ dtw,
                                               const float* __restrict__ dtb,
                                               const float* __restrict__ A_logs,
                                               float* __restrict__ carrA,
                                               float* __restrict__ carrH) {
    int bid = blockIdx.x;
    int c = bid & 63;
    int k = (bid >> 6) & 3;
    int b = bid >> 8;
    int d = threadIdx.x;
    int kd = k * DI + d;
    float Ac[16];
    #pragma unroll
    for (int i = 0; i < 4; ++i) {
        float4 v = *(const float4*)(A_logs + (size_t)kd * 16 + i * 4);
        Ac[i * 4 + 0] = -__expf(v.x); Ac[i * 4 + 1] = -__expf(v.y);
        Ac[i * 4 + 2] = -__expf(v.z); Ac[i * 4 + 3] = -__expf(v.w);
    }
    float wr[8];
    {
        float4 v0 = *(const float4*)(dtw + (size_t)kd * 8);
        float4 v1 = *(const float4*)(dtw + (size_t)kd * 8 + 4);
        wr[0] = v0.x; wr[1] = v0.y; wr[2] = v0.z; wr[3] = v0.w;
        wr[4] = v1.x; wr[5] = v1.y; wr[6] = v1.z; wr[7] = v1.w;
    }
    float bias = dtb[kd];
    float h[16];
    #pragma unroll
    for (int n = 0; n < 16; ++n) h[n] = 0.f;
    float sde = 0.f;
    const float* xb = xcS + (size_t)b * LL * DI;
    const float* sp = SP + (size_t)(b * Kn + k) * LL * 40;
    int t0 = c * CHUNK;
    for (int tt = 0; tt < CHUNK; ++tt) {
        int t = t0 + tt;
        const float* rec = sp + (size_t)t * 40;
        float4 q0 = *(const float4*)rec;
        float4 q1 = *(const float4*)(rec + 4);
        float dtv = bias + wr[0] * q0.x + wr[1] * q0.y + wr[2] * q0.z + wr[3] * q0.w
                         + wr[4] * q1.x + wr[5] * q1.y + wr[6] * q1.z + wr[7] * q1.w;
        float de = softplus_f(dtv);
        float u = xb[(size_t)posk(k, t) * DI + d];
        float du = de * u;
        sde += de;
        float Ba[16];
        #pragma unroll
        for (int i = 0; i < 4; ++i) {
            float4 v = *(const float4*)(rec + 8 + i * 4);
            Ba[i * 4 + 0] = v.x; Ba[i * 4 + 1] = v.y; Ba[i * 4 + 2] = v.z; Ba[i * 4 + 3] = v.w;
        }
        #pragma unroll
        for (int n = 0; n < 16; ++n)
            h[n] = __expf(de * Ac[n]) * h[n] + du * Ba[n];
    }
    size_t base = ((size_t)((b * Kn + k) * NC + c) * 16) * 256 + d;
    #pragma unroll
    for (int n = 0; n < 16; ++n) {
        carrA[base + n * 256] = __expf(Ac[n] * sde);
        carrH[base + n * 256] = h[n];
    }
}

// ---------- kernel 5: scan phase 2 — combine carries across chunks (in-place h_init) ----------
// grid 256 ; block 256 ; thread = (bk,n,d)
__global__ __launch_bounds__(256) void k_scan2(const float* __restrict__ carrA,
                                               float* __restrict__ carrH) {
    int gid = blockIdx.x * 256 + threadIdx.x;
    int d = gid & 255;
    int n = (gid >> 8) & 15;
    int bk = gid >> 12;
    size_t base = ((size_t)bk * NC * 16 + n) * 256 + d;
    const size_t cs = (size_t)16 * 256;
    float hr = 0.f;
    for (int c = 0; c < NC; ++c) {
        size_t idx = base + (size_t)c * cs;
        float a = carrA[idx];
        float he = carrH[idx];
        carrH[idx] = hr;       // h_init for chunk c
        hr = a * hr + he;
    }
}

// ---------- kernel 6: scan phase 3 — re-scan chunk from h_init, emit y ----------
// grid 1024 ; block 256 (thread = d)
__global__ __launch_bounds__(256) void k_scan3(const float* __restrict__ xcS,
                                               const float* __restrict__ SP,
                                               const float* __restrict__ dtw,
                                               const float* __restrict__ dtb,
                                               const float* __restrict__ A_logs,
                                               const float* __restrict__ Ds,
                                               const float* __restrict__ carrH,
                                               float* __restrict__ y) {
    int bid = blockIdx.x;
    int c = bid & 63;
    int k = (bid >> 6) & 3;
    int b = bid >> 8;
    int d = threadIdx.x;
    int kd = k * DI + d;
    float Ac[16];
    #pragma unroll
    for (int i = 0; i < 4; ++i) {
        float4 v = *(const float4*)(A_logs + (size_t)kd * 16 + i * 4);
        Ac[i * 4 + 0] = -__expf(v.x); Ac[i * 4 + 1] = -__expf(v.y);
        Ac[i * 4 + 2] = -__expf(v.z); Ac[i * 4 + 3] = -__expf(v.w);
    }
    float wr[8];
    {
        float4 v0 = *(const float4*)(dtw + (size_t)kd * 8);
        float4 v1 = *(const float4*)(dtw + (size_t)kd * 8 + 4);
        wr[0] = v0.x; wr[1] = v0.y; wr[2] = v0.z; wr[3] = v0.w;
        wr[4] = v1.x; wr[5] = v1.y; wr[6] = v1.z; wr[7] = v1.w;
    }
    float bias = dtb[kd];
    float Dv = Ds[kd];
    float h[16];
    size_t cbase = ((size_t)((b * Kn + k) * NC + c) * 16) * 256 + d;
    #pragma unroll
    for (int n = 0; n < 16; ++n) h[n] = carrH[cbase + n * 256];
    const float* xb = xcS + (size_t)b * LL * DI;
    const float* sp = SP + (size_t)(b * Kn + k) * LL * 40;
    float* yb = y + (size_t)b * LL * DI + d;
    int t0 = c * CHUNK;
    for (int tt = 0; tt < CHUNK; ++tt) {
        int t = t0 + tt;
        const float* rec = sp + (size_t)t * 40;
        float4 q0 = *(const float4*)rec;
        float4 q1 = *(const float4*)(rec + 4);
        float dtv = bias + wr[0] * q0.x + wr[1] * q0.y + wr[2] * q0.z + wr[3] * q0.w
                         + wr[4] * q1.x + wr[5] * q1.y + wr[6] * q1.z + wr[7] * q1.w;
        float de = softplus_f(dtv);
        int pos = posk(k, t);
        float u = xb[(size_t)pos * DI + d];
        float du = de * u;
        float Ba[16], Ca[16];
        #pragma unroll
        for (int i = 0; i < 4; ++i) {
            float4 v = *(const float4*)(rec + 8 + i * 4);
            Ba[i * 4 + 0] = v.x; Ba[i * 4 + 1] = v.y; Ba[i * 4 + 2] = v.z; Ba[i * 4 + 3] = v.w;
            float4 w = *(const float4*)(rec + 24 + i * 4);
            Ca[i * 4 + 0] = w.x; Ca[i * 4 + 1] = w.y; Ca[i * 4 + 2] = w.z; Ca[i * 4 + 3] = w.w;
        }
        float yv = Dv * u;
        #pragma unroll
        for (int n = 0; n < 16; ++n) {
            h[n] = __expf(de * Ac[n]) * h[n] + du * Ba[n];
            yv += h[n] * Ca[n];
        }
        atomicAdd(yb + (size_t)pos * DI, yv);
    }
}

// ---------- kernel 7: LayerNorm over last dim (in-place on d_out) ----------
// grid 16384 rows ; block 256
__global__ __launch_bounds__(256) void k_ln(float* __restrict__ y,
                                            const float* __restrict__ gamma,
                                            const float* __restrict__ beta) {
    __shared__ float s1[4], s2[4];
    int r = blockIdx.x;
    int tid = threadIdx.x;
    float v = y[(size_t)r * DI + tid];
    float a = v, bsq = v * v;
    #pragma unroll
    for (int off = 32; off; off >>= 1) {
        a += __shfl_xor(a, off);
        bsq += __shfl_xor(bsq, off);
    }
    if ((tid & 63) == 0) { s1[tid >> 6] = a; s2[tid >> 6] = bsq; }
    __syncthreads();
    float S1 = s1[0] + s1[1] + s1[2] + s1[3];
    float S2 = s2[0] + s2[1] + s2[2] + s2[3];
    float mu = S1 * (1.f / 256.f);
    float var = S2 * (1.f / 256.f) - mu * mu;
    float rs = rsqrtf(var + 1e-5f);
    y[(size_t)r * DI + tid] = (v - mu) * rs * gamma[tid] + beta[tid];
}

// ---------- launch ----------
extern "C" void kernel_launch(void* const* d_in, const int* in_sizes, int n_in,
                              void* d_out, int out_size, void* d_ws, size_t ws_size,
                              hipStream_t stream) {
    const float* x    = (const float*)d_in[0];
    const float* ipw  = (const float*)d_in[1];
    const float* cw   = (const float*)d_in[2];
    const float* cb   = (const float*)d_in[3];
    const float* xpw  = (const float*)d_in[4];
    const float* dtw  = (const float*)d_in[5];
    const float* dtb  = (const float*)d_in[6];
    const float* alog = (const float*)d_in[7];
    const float* Ds   = (const float*)d_in[8];
    const float* gam  = (const float*)d_in[9];
    const float* bet  = (const float*)d_in[10];

    // ws layout (bytes):
    //   [0, 16777216)           carrA (fp32 B*K*NC*N*DI)   -- aliases xls_pre[0:16.8M] (in_proj out, dead after conv)
    //   [16777216, 33554432)    carrH (fp32 B*K*NC*N*DI)
    //   [33554432, 50331648)    xcS   (fp32 B*L*DI, channel-last conv+SiLU output)
    //   [50331648, 60817408)    SP    (fp32 B*K*L*40 scan records: dts|B|C)
    const size_t WS_NEED = 60817408;
    if (ws_size < WS_NEED) return;

    char* ws = (char*)d_ws;
    float* carrA   = (float*)(ws + 0);
    float* carrH   = (float*)(ws + 16777216);
    float* xls_pre = (float*)(ws + 0);           // alias over carries (dead before scan1)
    float* xcS     = (float*)(ws + 33554432);
    float* SP      = (float*)(ws + 50331648);
    float* y       = (float*)d_out;

    hipMemsetAsync(d_out, 0, (size_t)out_size * sizeof(float), stream);
    k_inproj<<<1024,  256, 0, stream>>>(x, ipw, xls_pre);
    k_conv  <<<512,   256, 0, stream>>>(xls_pre, cw, cb, xcS);
    k_xdbl  <<<256,   256, 0, stream>>>(xcS, xpw, SP);
    k_scan1 <<<1024,  256, 0, stream>>>(xcS, SP, dtw, dtb, alog, carrA, carrH);
    k_scan2 <<<256,   256, 0, stream>>>(carrA, carrH);
    k_scan3 <<<1024,  256, 0, stream>>>(xcS, SP, dtw, dtb, alog, Ds, carrH, y);
    k_ln    <<<16384, 256, 0, stream>>>(y, gam, bet);
}

// Round 3
// 314.880 us; speedup vs baseline: 3.5736x; 1.2375x over previous
//
#include <hip/hip_runtime.h>

constexpr int Bn = 4;
constexpr int Hn = 64;
constexpr int Wn = 64;
constexpr int LL = Hn * Wn;     // 4096
constexpr int DM = 128;
constexpr int DI = 256;
constexpr int Nn = 16;
constexpr int Rn = 8;
constexpr int Kn = 4;
constexpr int NC = 64;          // chunks per (b,k) scan
constexpr int CHUNK = LL / NC;  // 64

// ---------- helpers ----------
__device__ __forceinline__ float softplus_f(float x) {
    if (x > 20.f) return x;
    return __logf(1.f + __expf(x));
}
// scan-order index t -> image position (row-major h*64+w)
__device__ __forceinline__ int posk(int k, int t) {
    int q = (k >= 2) ? (LL - 1 - t) : t;
    return (k & 1) ? (((q & 63) << 6) | (q >> 6)) : q;
}

// ---------- kernel 1: in_proj GEMM: xp[b,l,d] = sum_c x[b,l,c]*W[d,c] ----------
// grid 1024 = 64 ltiles * 4 dtiles * 4 b ; block 256
__global__ __launch_bounds__(256) void k_inproj(const float* __restrict__ x,
                                                const float* __restrict__ wp,
                                                float* __restrict__ out) {
    __shared__ float sx[64][68];  // [c][l]
    __shared__ float sw[64][68];  // [c][d]
    int bid = blockIdx.x;
    int lt = bid & 63;
    int dt = (bid >> 6) & 3;
    int b  = bid >> 8;
    int l0 = lt * 64, d0 = dt * 64;
    int tid = threadIdx.x;
    int dy = tid & 15;    // d-subtile (fast -> coalesced stores over d)
    int lx = tid >> 4;    // l-subtile
    float acc[4][4] = {}; // [d][l]
    for (int kc0 = 0; kc0 < DM; kc0 += 64) {
        #pragma unroll
        for (int i = 0; i < 4; ++i) {
            int idx = tid + i * 256;
            int row = idx >> 4, c4 = idx & 15;
            float4 v = *(const float4*)(x + ((size_t)b * LL + l0 + row) * DM + kc0 + c4 * 4);
            sx[c4 * 4 + 0][row] = v.x; sx[c4 * 4 + 1][row] = v.y;
            sx[c4 * 4 + 2][row] = v.z; sx[c4 * 4 + 3][row] = v.w;
            float4 u = *(const float4*)(wp + (size_t)(d0 + row) * DM + kc0 + c4 * 4);
            sw[c4 * 4 + 0][row] = u.x; sw[c4 * 4 + 1][row] = u.y;
            sw[c4 * 4 + 2][row] = u.z; sw[c4 * 4 + 3][row] = u.w;
        }
        __syncthreads();
        #pragma unroll 8
        for (int kc = 0; kc < 64; ++kc) {
            float4 xv = *(const float4*)&sx[kc][lx * 4];
            float4 wv = *(const float4*)&sw[kc][dy * 4];
            float xa[4] = {xv.x, xv.y, xv.z, xv.w};
            float wa[4] = {wv.x, wv.y, wv.z, wv.w};
            #pragma unroll
            for (int i = 0; i < 4; ++i)
                #pragma unroll
                for (int j = 0; j < 4; ++j)
                    acc[i][j] += wa[i] * xa[j];
        }
        __syncthreads();
    }
    // store channel-last: out[(b*LL + l)*DI + d], float4 over d
    #pragma unroll
    for (int j = 0; j < 4; ++j) {
        float4 v = {acc[0][j], acc[1][j], acc[2][j], acc[3][j]};
        *(float4*)(out + ((size_t)b * LL + l0 + lx * 4 + j) * DI + d0 + dy * 4) = v;
    }
}

// ---------- kernel 2: depthwise 3x3 conv + bias + SiLU, channel-last ----------
// grid 512 = 4b * 4dblk * 16wblk * 2hhalf ; block 256 = 64 d-lanes * 4 w
__global__ __launch_bounds__(256) void k_conv(const float* __restrict__ xin,
                                              const float* __restrict__ cw,
                                              const float* __restrict__ cb,
                                              float* __restrict__ xout) {
    int bid = blockIdx.x;
    int hh   = bid & 1;
    int wblk = (bid >> 1) & 15;
    int dblk = (bid >> 5) & 3;
    int b    = bid >> 7;
    int tid = threadIdx.x;
    int d = dblk * 64 + (tid & 63);
    int w = wblk * 4 + (tid >> 6);
    const float* inb = xin + (size_t)b * LL * DI + d;
    float* outb = xout + (size_t)b * LL * DI + d;
    float wg[9];
    #pragma unroll
    for (int i = 0; i < 9; ++i) wg[i] = cw[d * 9 + i];
    float bias = cb[d];
    #define LDV(hhh, www) ((((www) >= 0) && ((www) < Wn)) ? inb[(size_t)((hhh) * Wn + (www)) * DI] : 0.f)
    int hs = hh * 32;
    float r0[3], r1[3], r2[3];
    if (hs == 0) { r0[0] = r0[1] = r0[2] = 0.f; }
    else { r0[0] = LDV(hs - 1, w - 1); r0[1] = LDV(hs - 1, w); r0[2] = LDV(hs - 1, w + 1); }
    r1[0] = LDV(hs, w - 1); r1[1] = LDV(hs, w); r1[2] = LDV(hs, w + 1);
    r2[0] = LDV(hs + 1, w - 1); r2[1] = LDV(hs + 1, w); r2[2] = LDV(hs + 1, w + 1);
    for (int h = hs; h < hs + 32; ++h) {
        float acc = bias + wg[0] * r0[0] + wg[1] * r0[1] + wg[2] * r0[2]
                         + wg[3] * r1[0] + wg[4] * r1[1] + wg[5] * r1[2]
                         + wg[6] * r2[0] + wg[7] * r2[1] + wg[8] * r2[2];
        float sig = 1.f / (1.f + __expf(-acc));
        outb[(size_t)(h * Wn + w) * DI] = acc * sig;
        r0[0] = r1[0]; r0[1] = r1[1]; r0[2] = r1[2];
        r1[0] = r2[0]; r1[1] = r2[1]; r1[2] = r2[2];
        if (h + 2 < Hn) { r2[0] = LDV(h + 2, w - 1); r2[1] = LDV(h + 2, w); r2[2] = LDV(h + 2, w + 1); }
        else { r2[0] = r2[1] = r2[2] = 0.f; }
    }
    #undef LDV
}

// ---------- kernel 3: projection GEMM (gather-free, all 4 directions at once) ----------
// P[(b*LL+pos)*160 + k*40 + c] = sum_d xpw[k*40+c][d] * xcS[b,pos,d]
// grid 256 = 4b * 64 rowtiles(64) ; block 512 = 16 rt(4 rows) x 32 ct(5 cols)
__global__ __launch_bounds__(512) void k_proj(const float* __restrict__ xcS,
                                              const float* __restrict__ xpw,
                                              float* __restrict__ P) {
    __shared__ float sX[32][68];    // [kk][row]
    __shared__ float sW[32][164];   // [kk][c]
    int bid = blockIdx.x;
    int r0 = (bid & 63) * 64;
    int b = bid >> 6;
    int tid = threadIdx.x;
    int ct = tid & 31;   // cols c0 = ct*5
    int rt = tid >> 5;   // rows r = rt*4 .. +3
    float acc[4][5] = {};
    const float* Xb = xcS + ((size_t)b * LL + r0) * DI;
    for (int k0 = 0; k0 < DI; k0 += 32) {
        {
            int row = tid >> 3, k4 = tid & 7;     // 512 float4 = 64 rows x 32 kk
            float4 v = *(const float4*)(Xb + (size_t)row * DI + k0 + k4 * 4);
            sX[k4 * 4 + 0][row] = v.x; sX[k4 * 4 + 1][row] = v.y;
            sX[k4 * 4 + 2][row] = v.z; sX[k4 * 4 + 3][row] = v.w;
        }
        for (int i = tid; i < 1280; i += 512) {   // 160 c x 32 kk
            int c = i >> 3, k4 = i & 7;
            float4 v = *(const float4*)(xpw + (size_t)c * DI + k0 + k4 * 4);
            sW[k4 * 4 + 0][c] = v.x; sW[k4 * 4 + 1][c] = v.y;
            sW[k4 * 4 + 2][c] = v.z; sW[k4 * 4 + 3][c] = v.w;
        }
        __syncthreads();
        #pragma unroll 4
        for (int kk = 0; kk < 32; ++kk) {
            float4 xv = *(const float4*)&sX[kk][rt * 4];
            float xa[4] = {xv.x, xv.y, xv.z, xv.w};
            float wa[5];
            #pragma unroll
            for (int j = 0; j < 5; ++j) wa[j] = sW[kk][ct * 5 + j];
            #pragma unroll
            for (int i = 0; i < 4; ++i)
                #pragma unroll
                for (int j = 0; j < 5; ++j) acc[i][j] += xa[i] * wa[j];
        }
        __syncthreads();
    }
    float* ob = P + ((size_t)b * LL + r0 + rt * 4) * 160 + ct * 5;
    #pragma unroll
    for (int i = 0; i < 4; ++i)
        #pragma unroll
        for (int j = 0; j < 5; ++j) ob[(size_t)i * 160 + j] = acc[i][j];
}

// ---------- kernel 4: scan phase 1 — per-chunk local scan, emit carries ----------
// grid 1024 = 4b*4k*64c ; block 256 (thread = d)
__global__ __launch_bounds__(256) void k_scan1(const float* __restrict__ xcS,
                                               const float* __restrict__ P,
                                               const float* __restrict__ dtw,
                                               const float* __restrict__ dtb,
                                               const float* __restrict__ A_logs,
                                               float* __restrict__ carrA,
                                               float* __restrict__ carrH) {
    int bid = blockIdx.x;
    int c = bid & 63;
    int k = (bid >> 6) & 3;
    int b = bid >> 8;
    int d = threadIdx.x;
    int kd = k * DI + d;
    float Ac[16];
    #pragma unroll
    for (int i = 0; i < 4; ++i) {
        float4 v = *(const float4*)(A_logs + (size_t)kd * 16 + i * 4);
        Ac[i * 4 + 0] = -__expf(v.x); Ac[i * 4 + 1] = -__expf(v.y);
        Ac[i * 4 + 2] = -__expf(v.z); Ac[i * 4 + 3] = -__expf(v.w);
    }
    float wr[8];
    {
        float4 v0 = *(const float4*)(dtw + (size_t)kd * 8);
        float4 v1 = *(const float4*)(dtw + (size_t)kd * 8 + 4);
        wr[0] = v0.x; wr[1] = v0.y; wr[2] = v0.z; wr[3] = v0.w;
        wr[4] = v1.x; wr[5] = v1.y; wr[6] = v1.z; wr[7] = v1.w;
    }
    float bias = dtb[kd];
    float h[16];
    #pragma unroll
    for (int n = 0; n < 16; ++n) h[n] = 0.f;
    float sde = 0.f;
    const float* xb = xcS + (size_t)b * LL * DI;
    const float* Pb = P + (size_t)b * LL * 160 + k * 40;
    int t0 = c * CHUNK;
    for (int tt = 0; tt < CHUNK; ++tt) {
        int t = t0 + tt;
        int pos = posk(k, t);
        const float* rec = Pb + (size_t)pos * 160;
        float4 q0 = *(const float4*)rec;
        float4 q1 = *(const float4*)(rec + 4);
        float dtv = bias + wr[0] * q0.x + wr[1] * q0.y + wr[2] * q0.z + wr[3] * q0.w
                         + wr[4] * q1.x + wr[5] * q1.y + wr[6] * q1.z + wr[7] * q1.w;
        float de = softplus_f(dtv);
        float u = xb[(size_t)pos * DI + d];
        float du = de * u;
        sde += de;
        float Ba[16];
        #pragma unroll
        for (int i = 0; i < 4; ++i) {
            float4 v = *(const float4*)(rec + 8 + i * 4);
            Ba[i * 4 + 0] = v.x; Ba[i * 4 + 1] = v.y; Ba[i * 4 + 2] = v.z; Ba[i * 4 + 3] = v.w;
        }
        #pragma unroll
        for (int n = 0; n < 16; ++n)
            h[n] = __expf(de * Ac[n]) * h[n] + du * Ba[n];
    }
    size_t base = ((size_t)((b * Kn + k) * NC + c) * 16) * 256 + d;
    #pragma unroll
    for (int n = 0; n < 16; ++n) {
        carrA[base + n * 256] = __expf(Ac[n] * sde);
        carrH[base + n * 256] = h[n];
    }
}

// ---------- kernel 5: scan phase 2 — combine carries (register-preloaded) ----------
// grid 256 ; block 256 ; thread = (bk,n,d)
__global__ __launch_bounds__(256) void k_scan2(const float* __restrict__ carrA,
                                               float* __restrict__ carrH) {
    int gid = blockIdx.x * 256 + threadIdx.x;
    int d = gid & 255;
    int n = (gid >> 8) & 15;
    int bk = gid >> 12;
    size_t base = ((size_t)bk * NC * 16 + n) * 256 + d;
    const size_t cs = (size_t)16 * 256;
    float av[NC], hv[NC];
    #pragma unroll
    for (int c = 0; c < NC; ++c) av[c] = carrA[base + c * cs];
    #pragma unroll
    for (int c = 0; c < NC; ++c) hv[c] = carrH[base + c * cs];
    float hr = 0.f;
    #pragma unroll
    for (int c = 0; c < NC; ++c) {
        carrH[base + c * cs] = hr;       // h_init for chunk c
        hr = av[c] * hr + hv[c];
    }
}

// ---------- kernel 6: scan phase 3 — re-scan chunk from h_init, emit y ----------
// grid 1024 ; block 256 (thread = d)
__global__ __launch_bounds__(256) void k_scan3(const float* __restrict__ xcS,
                                               const float* __restrict__ P,
                                               const float* __restrict__ dtw,
                                               const float* __restrict__ dtb,
                                               const float* __restrict__ A_logs,
                                               const float* __restrict__ Ds,
                                               const float* __restrict__ carrH,
                                               float* __restrict__ y) {
    int bid = blockIdx.x;
    int c = bid & 63;
    int k = (bid >> 6) & 3;
    int b = bid >> 8;
    int d = threadIdx.x;
    int kd = k * DI + d;
    float Ac[16];
    #pragma unroll
    for (int i = 0; i < 4; ++i) {
        float4 v = *(const float4*)(A_logs + (size_t)kd * 16 + i * 4);
        Ac[i * 4 + 0] = -__expf(v.x); Ac[i * 4 + 1] = -__expf(v.y);
        Ac[i * 4 + 2] = -__expf(v.z); Ac[i * 4 + 3] = -__expf(v.w);
    }
    float wr[8];
    {
        float4 v0 = *(const float4*)(dtw + (size_t)kd * 8);
        float4 v1 = *(const float4*)(dtw + (size_t)kd * 8 + 4);
        wr[0] = v0.x; wr[1] = v0.y; wr[2] = v0.z; wr[3] = v0.w;
        wr[4] = v1.x; wr[5] = v1.y; wr[6] = v1.z; wr[7] = v1.w;
    }
    float bias = dtb[kd];
    float Dv = Ds[kd];
    float h[16];
    size_t cbase = ((size_t)((b * Kn + k) * NC + c) * 16) * 256 + d;
    #pragma unroll
    for (int n = 0; n < 16; ++n) h[n] = carrH[cbase + n * 256];
    const float* xb = xcS + (size_t)b * LL * DI;
    const float* Pb = P + (size_t)b * LL * 160 + k * 40;
    float* yb = y + (size_t)b * LL * DI + d;
    int t0 = c * CHUNK;
    for (int tt = 0; tt < CHUNK; ++tt) {
        int t = t0 + tt;
        int pos = posk(k, t);
        const float* rec = Pb + (size_t)pos * 160;
        float4 q0 = *(const float4*)rec;
        float4 q1 = *(const float4*)(rec + 4);
        float dtv = bias + wr[0] * q0.x + wr[1] * q0.y + wr[2] * q0.z + wr[3] * q0.w
                         + wr[4] * q1.x + wr[5] * q1.y + wr[6] * q1.z + wr[7] * q1.w;
        float de = softplus_f(dtv);
        float u = xb[(size_t)pos * DI + d];
        float du = de * u;
        float Ba[16], Ca[16];
        #pragma unroll
        for (int i = 0; i < 4; ++i) {
            float4 v = *(const float4*)(rec + 8 + i * 4);
            Ba[i * 4 + 0] = v.x; Ba[i * 4 + 1] = v.y; Ba[i * 4 + 2] = v.z; Ba[i * 4 + 3] = v.w;
            float4 w = *(const float4*)(rec + 24 + i * 4);
            Ca[i * 4 + 0] = w.x; Ca[i * 4 + 1] = w.y; Ca[i * 4 + 2] = w.z; Ca[i * 4 + 3] = w.w;
        }
        float yv = Dv * u;
        #pragma unroll
        for (int n = 0; n < 16; ++n) {
            h[n] = __expf(de * Ac[n]) * h[n] + du * Ba[n];
            yv += h[n] * Ca[n];
        }
        atomicAdd(yb + (size_t)pos * DI, yv);
    }
}

// ---------- kernel 7: LayerNorm over last dim (in-place on d_out) ----------
// grid 16384 rows ; block 256
__global__ __launch_bounds__(256) void k_ln(float* __restrict__ y,
                                            const float* __restrict__ gamma,
                                            const float* __restrict__ beta) {
    __shared__ float s1[4], s2[4];
    int r = blockIdx.x;
    int tid = threadIdx.x;
    float v = y[(size_t)r * DI + tid];
    float a = v, bsq = v * v;
    #pragma unroll
    for (int off = 32; off; off >>= 1) {
        a += __shfl_xor(a, off);
        bsq += __shfl_xor(bsq, off);
    }
    if ((tid & 63) == 0) { s1[tid >> 6] = a; s2[tid >> 6] = bsq; }
    __syncthreads();
    float S1 = s1[0] + s1[1] + s1[2] + s1[3];
    float S2 = s2[0] + s2[1] + s2[2] + s2[3];
    float mu = S1 * (1.f / 256.f);
    float var = S2 * (1.f / 256.f) - mu * mu;
    float rs = rsqrtf(var + 1e-5f);
    y[(size_t)r * DI + tid] = (v - mu) * rs * gamma[tid] + beta[tid];
}

// ---------- launch ----------
extern "C" void kernel_launch(void* const* d_in, const int* in_sizes, int n_in,
                              void* d_out, int out_size, void* d_ws, size_t ws_size,
                              hipStream_t stream) {
    const float* x    = (const float*)d_in[0];
    const float* ipw  = (const float*)d_in[1];
    const float* cw   = (const float*)d_in[2];
    const float* cb   = (const float*)d_in[3];
    const float* xpw  = (const float*)d_in[4];
    const float* dtw  = (const float*)d_in[5];
    const float* dtb  = (const float*)d_in[6];
    const float* alog = (const float*)d_in[7];
    const float* Ds   = (const float*)d_in[8];
    const float* gam  = (const float*)d_in[9];
    const float* bet  = (const float*)d_in[10];

    // ws layout (bytes):
    //   [0, 16777216)           carrA (fp32 B*K*NC*N*DI)   -- aliases xls_pre (in_proj out, dead after conv)
    //   [16777216, 33554432)    carrH (fp32 B*K*NC*N*DI)
    //   [33554432, 50331648)    xcS   (fp32 B*L*DI, channel-last conv+SiLU output)
    //   [50331648, 60817408)    P     (fp32 B*L*160 projection records, image order: [k*40: dts|B|C])
    const size_t WS_NEED = 60817408;
    if (ws_size < WS_NEED) return;

    char* ws = (char*)d_ws;
    float* carrA   = (float*)(ws + 0);
    float* carrH   = (float*)(ws + 16777216);
    float* xls_pre = (float*)(ws + 0);           // alias over carries (dead before scan1)
    float* xcS     = (float*)(ws + 33554432);
    float* P       = (float*)(ws + 50331648);
    float* y       = (float*)d_out;

    hipMemsetAsync(d_out, 0, (size_t)out_size * sizeof(float), stream);
    k_inproj<<<1024,  256, 0, stream>>>(x, ipw, xls_pre);
    k_conv  <<<512,   256, 0, stream>>>(xls_pre, cw, cb, xcS);
    k_proj  <<<256,   512, 0, stream>>>(xcS, xpw, P);
    k_scan1 <<<1024,  256, 0, stream>>>(xcS, P, dtw, dtb, alog, carrA, carrH);
    k_scan2 <<<256,   256, 0, stream>>>(carrA, carrH);
    k_scan3 <<<1024,  256, 0, stream>>>(xcS, P, dtw, dtb, alog, Ds, carrH, y);
    k_ln    <<<16384, 256, 0, stream>>>(y, gam, bet);
}

// Round 4
// 299.864 us; speedup vs baseline: 3.7526x; 1.0501x over previous
//
#include <hip/hip_runtime.h>

constexpr int Bn = 4;
constexpr int Hn = 64;
constexpr int Wn = 64;
constexpr int LL = Hn * Wn;     // 4096
constexpr int DM = 128;
constexpr int DI = 256;
constexpr int Nn = 16;
constexpr int Rn = 8;
constexpr int Kn = 4;
constexpr int NC = 64;          // chunks per (b,k) scan
constexpr int CHUNK = LL / NC;  // 64

// ---------- helpers ----------
__device__ __forceinline__ float softplus_f(float x) {
    if (x > 20.f) return x;
    return __logf(1.f + __expf(x));
}
// scan-order index t -> image position (row-major h*64+w)
__device__ __forceinline__ int posk(int k, int t) {
    int q = (k >= 2) ? (LL - 1 - t) : t;
    return (k & 1) ? (((q & 63) << 6) | (q >> 6)) : q;
}

// ---------- kernel 1: in_proj GEMM: xp[b,l,d] = sum_c x[b,l,c]*W[d,c] ----------
// grid 1024 = 64 ltiles * 4 dtiles * 4 b ; block 256
__global__ __launch_bounds__(256) void k_inproj(const float* __restrict__ x,
                                                const float* __restrict__ wp,
                                                float* __restrict__ out) {
    __shared__ float sx[64][68];  // [c][l]
    __shared__ float sw[64][68];  // [c][d]
    int bid = blockIdx.x;
    int lt = bid & 63;
    int dt = (bid >> 6) & 3;
    int b  = bid >> 8;
    int l0 = lt * 64, d0 = dt * 64;
    int tid = threadIdx.x;
    int dy = tid & 15;    // d-subtile (fast -> coalesced stores over d)
    int lx = tid >> 4;    // l-subtile
    float acc[4][4] = {}; // [d][l]
    for (int kc0 = 0; kc0 < DM; kc0 += 64) {
        #pragma unroll
        for (int i = 0; i < 4; ++i) {
            int idx = tid + i * 256;
            int row = idx >> 4, c4 = idx & 15;
            float4 v = *(const float4*)(x + ((size_t)b * LL + l0 + row) * DM + kc0 + c4 * 4);
            sx[c4 * 4 + 0][row] = v.x; sx[c4 * 4 + 1][row] = v.y;
            sx[c4 * 4 + 2][row] = v.z; sx[c4 * 4 + 3][row] = v.w;
            float4 u = *(const float4*)(wp + (size_t)(d0 + row) * DM + kc0 + c4 * 4);
            sw[c4 * 4 + 0][row] = u.x; sw[c4 * 4 + 1][row] = u.y;
            sw[c4 * 4 + 2][row] = u.z; sw[c4 * 4 + 3][row] = u.w;
        }
        __syncthreads();
        #pragma unroll 8
        for (int kc = 0; kc < 64; ++kc) {
            float4 xv = *(const float4*)&sx[kc][lx * 4];
            float4 wv = *(const float4*)&sw[kc][dy * 4];
            float xa[4] = {xv.x, xv.y, xv.z, xv.w};
            float wa[4] = {wv.x, wv.y, wv.z, wv.w};
            #pragma unroll
            for (int i = 0; i < 4; ++i)
                #pragma unroll
                for (int j = 0; j < 4; ++j)
                    acc[i][j] += wa[i] * xa[j];
        }
        __syncthreads();
    }
    // store channel-last: out[(b*LL + l)*DI + d], float4 over d
    #pragma unroll
    for (int j = 0; j < 4; ++j) {
        float4 v = {acc[0][j], acc[1][j], acc[2][j], acc[3][j]};
        *(float4*)(out + ((size_t)b * LL + l0 + lx * 4 + j) * DI + d0 + dy * 4) = v;
    }
}

// ---------- kernel 2: depthwise 3x3 conv + bias + SiLU, channel-last ----------
// grid 512 = 4b * 4dblk * 16wblk * 2hhalf ; block 256 = 64 d-lanes * 4 w
__global__ __launch_bounds__(256) void k_conv(const float* __restrict__ xin,
                                              const float* __restrict__ cw,
                                              const float* __restrict__ cb,
                                              float* __restrict__ xout) {
    int bid = blockIdx.x;
    int hh   = bid & 1;
    int wblk = (bid >> 1) & 15;
    int dblk = (bid >> 5) & 3;
    int b    = bid >> 7;
    int tid = threadIdx.x;
    int d = dblk * 64 + (tid & 63);
    int w = wblk * 4 + (tid >> 6);
    const float* inb = xin + (size_t)b * LL * DI + d;
    float* outb = xout + (size_t)b * LL * DI + d;
    float wg[9];
    #pragma unroll
    for (int i = 0; i < 9; ++i) wg[i] = cw[d * 9 + i];
    float bias = cb[d];
    #define LDV(hhh, www) ((((www) >= 0) && ((www) < Wn)) ? inb[(size_t)((hhh) * Wn + (www)) * DI] : 0.f)
    int hs = hh * 32;
    float r0[3], r1[3], r2[3];
    if (hs == 0) { r0[0] = r0[1] = r0[2] = 0.f; }
    else { r0[0] = LDV(hs - 1, w - 1); r0[1] = LDV(hs - 1, w); r0[2] = LDV(hs - 1, w + 1); }
    r1[0] = LDV(hs, w - 1); r1[1] = LDV(hs, w); r1[2] = LDV(hs, w + 1);
    r2[0] = LDV(hs + 1, w - 1); r2[1] = LDV(hs + 1, w); r2[2] = LDV(hs + 1, w + 1);
    for (int h = hs; h < hs + 32; ++h) {
        float acc = bias + wg[0] * r0[0] + wg[1] * r0[1] + wg[2] * r0[2]
                         + wg[3] * r1[0] + wg[4] * r1[1] + wg[5] * r1[2]
                         + wg[6] * r2[0] + wg[7] * r2[1] + wg[8] * r2[2];
        float sig = 1.f / (1.f + __expf(-acc));
        outb[(size_t)(h * Wn + w) * DI] = acc * sig;
        r0[0] = r1[0]; r0[1] = r1[1]; r0[2] = r1[2];
        r1[0] = r2[0]; r1[1] = r2[1]; r1[2] = r2[2];
        if (h + 2 < Hn) { r2[0] = LDV(h + 2, w - 1); r2[1] = LDV(h + 2, w); r2[2] = LDV(h + 2, w + 1); }
        else { r2[0] = r2[1] = r2[2] = 0.f; }
    }
    #undef LDV
}

// ---------- kernel 3: projection GEMM (gather-free, all 4 directions at once) ----------
// P[(b*LL+pos)*160 + k*40 + c] = sum_d xpw[k*40+c][d] * xcS[b,pos,d]
// grid 256 = 4b * 64 rowtiles(64) ; block 512 = 16 rt(4 rows) x 32 ct(5 cols)
__global__ __launch_bounds__(512) void k_proj(const float* __restrict__ xcS,
                                              const float* __restrict__ xpw,
                                              float* __restrict__ P) {
    __shared__ float sX[32][68];    // [kk][row]
    __shared__ float sW[32][164];   // [kk][c]
    int bid = blockIdx.x;
    int r0 = (bid & 63) * 64;
    int b = bid >> 6;
    int tid = threadIdx.x;
    int ct = tid & 31;   // cols c0 = ct*5
    int rt = tid >> 5;   // rows r = rt*4 .. +3
    float acc[4][5] = {};
    const float* Xb = xcS + ((size_t)b * LL + r0) * DI;
    for (int k0 = 0; k0 < DI; k0 += 32) {
        {
            int row = tid >> 3, k4 = tid & 7;     // 512 float4 = 64 rows x 32 kk
            float4 v = *(const float4*)(Xb + (size_t)row * DI + k0 + k4 * 4);
            sX[k4 * 4 + 0][row] = v.x; sX[k4 * 4 + 1][row] = v.y;
            sX[k4 * 4 + 2][row] = v.z; sX[k4 * 4 + 3][row] = v.w;
        }
        for (int i = tid; i < 1280; i += 512) {   // 160 c x 32 kk
            int c = i >> 3, k4 = i & 7;
            float4 v = *(const float4*)(xpw + (size_t)c * DI + k0 + k4 * 4);
            sW[k4 * 4 + 0][c] = v.x; sW[k4 * 4 + 1][c] = v.y;
            sW[k4 * 4 + 2][c] = v.z; sW[k4 * 4 + 3][c] = v.w;
        }
        __syncthreads();
        #pragma unroll 4
        for (int kk = 0; kk < 32; ++kk) {
            float4 xv = *(const float4*)&sX[kk][rt * 4];
            float xa[4] = {xv.x, xv.y, xv.z, xv.w};
            float wa[5];
            #pragma unroll
            for (int j = 0; j < 5; ++j) wa[j] = sW[kk][ct * 5 + j];
            #pragma unroll
            for (int i = 0; i < 4; ++i)
                #pragma unroll
                for (int j = 0; j < 5; ++j) acc[i][j] += xa[i] * wa[j];
        }
        __syncthreads();
    }
    float* ob = P + ((size_t)b * LL + r0 + rt * 4) * 160 + ct * 5;
    #pragma unroll
    for (int i = 0; i < 4; ++i)
        #pragma unroll
        for (int j = 0; j < 5; ++j) ob[(size_t)i * 160 + j] = acc[i][j];
}

// ---------- scan common: load per-(k,d) constants ----------
__device__ __forceinline__ void scan_consts(const float* __restrict__ A_logs,
                                            const float* __restrict__ dtw,
                                            int kd, float Ac[16], float wr[8], bool& chainable) {
    #pragma unroll
    for (int i = 0; i < 4; ++i) {
        float4 v = *(const float4*)(A_logs + (size_t)kd * 16 + i * 4);
        Ac[i * 4 + 0] = -__expf(v.x); Ac[i * 4 + 1] = -__expf(v.y);
        Ac[i * 4 + 2] = -__expf(v.z); Ac[i * 4 + 3] = -__expf(v.w);
    }
    float4 v0 = *(const float4*)(dtw + (size_t)kd * 8);
    float4 v1 = *(const float4*)(dtw + (size_t)kd * 8 + 4);
    wr[0] = v0.x; wr[1] = v0.y; wr[2] = v0.z; wr[3] = v0.w;
    wr[4] = v1.x; wr[5] = v1.y; wr[6] = v1.z; wr[7] = v1.w;
    // chainable iff Ac[n] == (n+1)*Ac[0] and Ac[0] == -1  (true for A_logs=log(1..16))
    chainable = fabsf(Ac[0] + 1.f) < 1e-6f;
    #pragma unroll
    for (int n = 1; n < 16; ++n)
        chainable = chainable && (fabsf(Ac[n] - (float)(n + 1) * Ac[0]) <= 1e-4f * fabsf(Ac[n]));
}

// softplus pieces: de = softplus(dtv), e1 = exp(-de) (exact identity: 1/(1+exp(dtv)))
__device__ __forceinline__ void softplus_e1(float dtv, float& de, float& e1) {
    if (dtv > 20.f) { de = dtv; e1 = __expf(-dtv); }
    else {
        float E = __expf(dtv);
        de = __logf(1.f + E);
        e1 = __builtin_amdgcn_rcpf(1.f + E);
    }
}

// ---------- kernel 4: scan phase 1 — per-chunk local scan, emit carries ----------
// grid 1024 = 4b*4k*64c ; block 256 (thread = d)
__global__ __launch_bounds__(256) void k_scan1(const float* __restrict__ xcS,
                                               const float* __restrict__ P,
                                               const float* __restrict__ dtw,
                                               const float* __restrict__ dtb,
                                               const float* __restrict__ A_logs,
                                               float* __restrict__ carrA,
                                               float* __restrict__ carrH) {
    int bid = blockIdx.x;
    int c = bid & 63;
    int k = (bid >> 6) & 3;
    int b = bid >> 8;
    int d = threadIdx.x;
    int kd = k * DI + d;
    float Ac[16], wr[8];
    bool chainable;
    scan_consts(A_logs, dtw, kd, Ac, wr, chainable);
    float bias = dtb[kd];
    float h[16];
    #pragma unroll
    for (int n = 0; n < 16; ++n) h[n] = 0.f;
    float sde = 0.f;
    const float* xb = xcS + (size_t)b * LL * DI;
    const float* Pb = P + (size_t)b * LL * 160 + k * 40;
    int t0 = c * CHUNK;
    if (chainable) {
        for (int tt = 0; tt < CHUNK; ++tt) {
            int t = t0 + tt;
            int pos = posk(k, t);
            const float* rec = Pb + (size_t)pos * 160;
            float4 q0 = *(const float4*)rec;
            float4 q1 = *(const float4*)(rec + 4);
            float dtv = bias + wr[0] * q0.x + wr[1] * q0.y + wr[2] * q0.z + wr[3] * q0.w
                             + wr[4] * q1.x + wr[5] * q1.y + wr[6] * q1.z + wr[7] * q1.w;
            float de, e1;
            softplus_e1(dtv, de, e1);
            float u = xb[(size_t)pos * DI + d];
            float du = de * u;
            sde += de;
            float Ba[16];
            #pragma unroll
            for (int i = 0; i < 4; ++i) {
                float4 v = *(const float4*)(rec + 8 + i * 4);
                Ba[i * 4 + 0] = v.x; Ba[i * 4 + 1] = v.y; Ba[i * 4 + 2] = v.z; Ba[i * 4 + 3] = v.w;
            }
            float en = e1;
            #pragma unroll
            for (int n = 0; n < 16; ++n) {
                h[n] = en * h[n] + du * Ba[n];
                en *= e1;
            }
        }
    } else {
        for (int tt = 0; tt < CHUNK; ++tt) {
            int t = t0 + tt;
            int pos = posk(k, t);
            const float* rec = Pb + (size_t)pos * 160;
            float4 q0 = *(const float4*)rec;
            float4 q1 = *(const float4*)(rec + 4);
            float dtv = bias + wr[0] * q0.x + wr[1] * q0.y + wr[2] * q0.z + wr[3] * q0.w
                             + wr[4] * q1.x + wr[5] * q1.y + wr[6] * q1.z + wr[7] * q1.w;
            float de = softplus_f(dtv);
            float u = xb[(size_t)pos * DI + d];
            float du = de * u;
            sde += de;
            float Ba[16];
            #pragma unroll
            for (int i = 0; i < 4; ++i) {
                float4 v = *(const float4*)(rec + 8 + i * 4);
                Ba[i * 4 + 0] = v.x; Ba[i * 4 + 1] = v.y; Ba[i * 4 + 2] = v.z; Ba[i * 4 + 3] = v.w;
            }
            #pragma unroll
            for (int n = 0; n < 16; ++n)
                h[n] = __expf(de * Ac[n]) * h[n] + du * Ba[n];
        }
    }
    size_t base = ((size_t)((b * Kn + k) * NC + c) * 16) * 256 + d;
    if (chainable) {
        float g1 = __expf(Ac[0] * sde);
        float g = g1;
        #pragma unroll
        for (int n = 0; n < 16; ++n) {
            carrA[base + n * 256] = g;
            carrH[base + n * 256] = h[n];
            g *= g1;
        }
    } else {
        #pragma unroll
        for (int n = 0; n < 16; ++n) {
            carrA[base + n * 256] = __expf(Ac[n] * sde);
            carrH[base + n * 256] = h[n];
        }
    }
}

// ---------- kernel 5: scan phase 2 — combine carries (register-preloaded) ----------
// grid 256 ; block 256 ; thread = (bk,n,d)
__global__ __launch_bounds__(256) void k_scan2(const float* __restrict__ carrA,
                                               float* __restrict__ carrH) {
    int gid = blockIdx.x * 256 + threadIdx.x;
    int d = gid & 255;
    int n = (gid >> 8) & 15;
    int bk = gid >> 12;
    size_t base = ((size_t)bk * NC * 16 + n) * 256 + d;
    const size_t cs = (size_t)16 * 256;
    float av[NC], hv[NC];
    #pragma unroll
    for (int c = 0; c < NC; ++c) av[c] = carrA[base + c * cs];
    #pragma unroll
    for (int c = 0; c < NC; ++c) hv[c] = carrH[base + c * cs];
    float hr = 0.f;
    #pragma unroll
    for (int c = 0; c < NC; ++c) {
        carrH[base + c * cs] = hr;       // h_init for chunk c
        hr = av[c] * hr + hv[c];
    }
}

// ---------- kernel 6: scan phase 3 — re-scan chunk from h_init, emit y ----------
// grid 1024 ; block 256 (thread = d)
__global__ __launch_bounds__(256) void k_scan3(const float* __restrict__ xcS,
                                               const float* __restrict__ P,
                                               const float* __restrict__ dtw,
                                               const float* __restrict__ dtb,
                                               const float* __restrict__ A_logs,
                                               const float* __restrict__ Ds,
                                               const float* __restrict__ carrH,
                                               float* __restrict__ y) {
    int bid = blockIdx.x;
    int c = bid & 63;
    int k = (bid >> 6) & 3;
    int b = bid >> 8;
    int d = threadIdx.x;
    int kd = k * DI + d;
    float Ac[16], wr[8];
    bool chainable;
    scan_consts(A_logs, dtw, kd, Ac, wr, chainable);
    float bias = dtb[kd];
    float Dv = Ds[kd];
    float h[16];
    size_t cbase = ((size_t)((b * Kn + k) * NC + c) * 16) * 256 + d;
    #pragma unroll
    for (int n = 0; n < 16; ++n) h[n] = carrH[cbase + n * 256];
    const float* xb = xcS + (size_t)b * LL * DI;
    const float* Pb = P + (size_t)b * LL * 160 + k * 40;
    float* yb = y + (size_t)b * LL * DI + d;
    int t0 = c * CHUNK;
    if (chainable) {
        for (int tt = 0; tt < CHUNK; ++tt) {
            int t = t0 + tt;
            int pos = posk(k, t);
            const float* rec = Pb + (size_t)pos * 160;
            float4 q0 = *(const float4*)rec;
            float4 q1 = *(const float4*)(rec + 4);
            float dtv = bias + wr[0] * q0.x + wr[1] * q0.y + wr[2] * q0.z + wr[3] * q0.w
                             + wr[4] * q1.x + wr[5] * q1.y + wr[6] * q1.z + wr[7] * q1.w;
            float de, e1;
            softplus_e1(dtv, de, e1);
            float u = xb[(size_t)pos * DI + d];
            float du = de * u;
            float Ba[16], Ca[16];
            #pragma unroll
            for (int i = 0; i < 4; ++i) {
                float4 v = *(const float4*)(rec + 8 + i * 4);
                Ba[i * 4 + 0] = v.x; Ba[i * 4 + 1] = v.y; Ba[i * 4 + 2] = v.z; Ba[i * 4 + 3] = v.w;
                float4 w = *(const float4*)(rec + 24 + i * 4);
                Ca[i * 4 + 0] = w.x; Ca[i * 4 + 1] = w.y; Ca[i * 4 + 2] = w.z; Ca[i * 4 + 3] = w.w;
            }
            float yv = Dv * u;
            float en = e1;
            #pragma unroll
            for (int n = 0; n < 16; ++n) {
                h[n] = en * h[n] + du * Ba[n];
                yv += h[n] * Ca[n];
                en *= e1;
            }
            atomicAdd(yb + (size_t)pos * DI, yv);
        }
    } else {
        for (int tt = 0; tt < CHUNK; ++tt) {
            int t = t0 + tt;
            int pos = posk(k, t);
            const float* rec = Pb + (size_t)pos * 160;
            float4 q0 = *(const float4*)rec;
            float4 q1 = *(const float4*)(rec + 4);
            float dtv = bias + wr[0] * q0.x + wr[1] * q0.y + wr[2] * q0.z + wr[3] * q0.w
                             + wr[4] * q1.x + wr[5] * q1.y + wr[6] * q1.z + wr[7] * q1.w;
            float de = softplus_f(dtv);
            float u = xb[(size_t)pos * DI + d];
            float du = de * u;
            float Ba[16], Ca[16];
            #pragma unroll
            for (int i = 0; i < 4; ++i) {
                float4 v = *(const float4*)(rec + 8 + i * 4);
                Ba[i * 4 + 0] = v.x; Ba[i * 4 + 1] = v.y; Ba[i * 4 + 2] = v.z; Ba[i * 4 + 3] = v.w;
                float4 w = *(const float4*)(rec + 24 + i * 4);
                Ca[i * 4 + 0] = w.x; Ca[i * 4 + 1] = w.y; Ca[i * 4 + 2] = w.z; Ca[i * 4 + 3] = w.w;
            }
            float yv = Dv * u;
            #pragma unroll
            for (int n = 0; n < 16; ++n) {
                h[n] = __expf(de * Ac[n]) * h[n] + du * Ba[n];
                yv += h[n] * Ca[n];
            }
            atomicAdd(yb + (size_t)pos * DI, yv);
        }
    }
}

// ---------- kernel 7: LayerNorm over last dim (in-place on d_out) ----------
// grid 16384 rows ; block 256
__global__ __launch_bounds__(256) void k_ln(float* __restrict__ y,
                                            const float* __restrict__ gamma,
                                            const float* __restrict__ beta) {
    __shared__ float s1[4], s2[4];
    int r = blockIdx.x;
    int tid = threadIdx.x;
    float v = y[(size_t)r * DI + tid];
    float a = v, bsq = v * v;
    #pragma unroll
    for (int off = 32; off; off >>= 1) {
        a += __shfl_xor(a, off);
        bsq += __shfl_xor(bsq, off);
    }
    if ((tid & 63) == 0) { s1[tid >> 6] = a; s2[tid >> 6] = bsq; }
    __syncthreads();
    float S1 = s1[0] + s1[1] + s1[2] + s1[3];
    float S2 = s2[0] + s2[1] + s2[2] + s2[3];
    float mu = S1 * (1.f / 256.f);
    float var = S2 * (1.f / 256.f) - mu * mu;
    float rs = rsqrtf(var + 1e-5f);
    y[(size_t)r * DI + tid] = (v - mu) * rs * gamma[tid] + beta[tid];
}

// ---------- launch ----------
extern "C" void kernel_launch(void* const* d_in, const int* in_sizes, int n_in,
                              void* d_out, int out_size, void* d_ws, size_t ws_size,
                              hipStream_t stream) {
    const float* x    = (const float*)d_in[0];
    const float* ipw  = (const float*)d_in[1];
    const float* cw   = (const float*)d_in[2];
    const float* cb   = (const float*)d_in[3];
    const float* xpw  = (const float*)d_in[4];
    const float* dtw  = (const float*)d_in[5];
    const float* dtb  = (const float*)d_in[6];
    const float* alog = (const float*)d_in[7];
    const float* Ds   = (const float*)d_in[8];
    const float* gam  = (const float*)d_in[9];
    const float* bet  = (const float*)d_in[10];

    // ws layout (bytes):
    //   [0, 16777216)           carrA (fp32 B*K*NC*N*DI)   -- aliases xls_pre (in_proj out, dead after conv)
    //   [16777216, 33554432)    carrH (fp32 B*K*NC*N*DI)
    //   [33554432, 50331648)    xcS   (fp32 B*L*DI, channel-last conv+SiLU output)
    //   [50331648, 60817408)    P     (fp32 B*L*160 projection records, image order: [k*40: dts|B|C])
    const size_t WS_NEED = 60817408;
    if (ws_size < WS_NEED) return;

    char* ws = (char*)d_ws;
    float* carrA   = (float*)(ws + 0);
    float* carrH   = (float*)(ws + 16777216);
    float* xls_pre = (float*)(ws + 0);           // alias over carries (dead before scan1)
    float* xcS     = (float*)(ws + 33554432);
    float* P       = (float*)(ws + 50331648);
    float* y       = (float*)d_out;

    hipMemsetAsync(d_out, 0, (size_t)out_size * sizeof(float), stream);
    k_inproj<<<1024,  256, 0, stream>>>(x, ipw, xls_pre);
    k_conv  <<<512,   256, 0, stream>>>(xls_pre, cw, cb, xcS);
    k_proj  <<<256,   512, 0, stream>>>(xcS, xpw, P);
    k_scan1 <<<1024,  256, 0, stream>>>(xcS, P, dtw, dtb, alog, carrA, carrH);
    k_scan2 <<<256,   256, 0, stream>>>(carrA, carrH);
    k_scan3 <<<1024,  256, 0, stream>>>(xcS, P, dtw, dtb, alog, Ds, carrH, y);
    k_ln    <<<16384, 256, 0, stream>>>(y, gam, bet);
}

// Round 5
// 284.990 us; speedup vs baseline: 3.9484x; 1.0522x over previous
//
#include <hip/hip_runtime.h>

constexpr int Bn = 4;
constexpr int Hn = 64;
constexpr int Wn = 64;
constexpr int LL = Hn * Wn;     // 4096
constexpr int DM = 128;
constexpr int DI = 256;
constexpr int Nn = 16;
constexpr int Rn = 8;
constexpr int Kn = 4;
constexpr int NC = 128;         // chunks per (b,k) scan
constexpr int CHUNK = LL / NC;  // 32

// ---------- helpers ----------
__device__ __forceinline__ float bf2f(unsigned short s) {
    return __uint_as_float(((unsigned int)s) << 16);
}
__device__ __forceinline__ unsigned short f2bf(float f) {
    unsigned int u = __float_as_uint(f);
    u += 0x7FFFu + ((u >> 16) & 1u);   // RNE
    return (unsigned short)(u >> 16);
}
__device__ __forceinline__ float softplus_f(float x) {
    if (x > 20.f) return x;
    return __logf(1.f + __expf(x));
}
// scan-order index t -> image position (row-major h*64+w)
__device__ __forceinline__ int posk(int k, int t) {
    int q = (k >= 2) ? (LL - 1 - t) : t;
    return (k & 1) ? (((q & 63) << 6) | (q >> 6)) : q;
}

// ---------- kernel 1: in_proj GEMM: xp[b,l,d] = sum_c x[b,l,c]*W[d,c] ----------
// grid 1024 = 64 ltiles * 4 dtiles * 4 b ; block 256
__global__ __launch_bounds__(256) void k_inproj(const float* __restrict__ x,
                                                const float* __restrict__ wp,
                                                float* __restrict__ out) {
    __shared__ float sx[64][68];  // [c][l]
    __shared__ float sw[64][68];  // [c][d]
    int bid = blockIdx.x;
    int lt = bid & 63;
    int dt = (bid >> 6) & 3;
    int b  = bid >> 8;
    int l0 = lt * 64, d0 = dt * 64;
    int tid = threadIdx.x;
    int dy = tid & 15;    // d-subtile (fast -> coalesced stores over d)
    int lx = tid >> 4;    // l-subtile
    float acc[4][4] = {}; // [d][l]
    for (int kc0 = 0; kc0 < DM; kc0 += 64) {
        #pragma unroll
        for (int i = 0; i < 4; ++i) {
            int idx = tid + i * 256;
            int row = idx >> 4, c4 = idx & 15;
            float4 v = *(const float4*)(x + ((size_t)b * LL + l0 + row) * DM + kc0 + c4 * 4);
            sx[c4 * 4 + 0][row] = v.x; sx[c4 * 4 + 1][row] = v.y;
            sx[c4 * 4 + 2][row] = v.z; sx[c4 * 4 + 3][row] = v.w;
            float4 u = *(const float4*)(wp + (size_t)(d0 + row) * DM + kc0 + c4 * 4);
            sw[c4 * 4 + 0][row] = u.x; sw[c4 * 4 + 1][row] = u.y;
            sw[c4 * 4 + 2][row] = u.z; sw[c4 * 4 + 3][row] = u.w;
        }
        __syncthreads();
        #pragma unroll 8
        for (int kc = 0; kc < 64; ++kc) {
            float4 xv = *(const float4*)&sx[kc][lx * 4];
            float4 wv = *(const float4*)&sw[kc][dy * 4];
            float xa[4] = {xv.x, xv.y, xv.z, xv.w};
            float wa[4] = {wv.x, wv.y, wv.z, wv.w};
            #pragma unroll
            for (int i = 0; i < 4; ++i)
                #pragma unroll
                for (int j = 0; j < 4; ++j)
                    acc[i][j] += wa[i] * xa[j];
        }
        __syncthreads();
    }
    // store channel-last: out[(b*LL + l)*DI + d], float4 over d
    #pragma unroll
    for (int j = 0; j < 4; ++j) {
        float4 v = {acc[0][j], acc[1][j], acc[2][j], acc[3][j]};
        *(float4*)(out + ((size_t)b * LL + l0 + lx * 4 + j) * DI + d0 + dy * 4) = v;
    }
}

// ---------- kernel 2: depthwise 3x3 conv + bias + SiLU, channel-last ----------
// grid 512 = 4b * 4dblk * 16wblk * 2hhalf ; block 256 = 64 d-lanes * 4 w
__global__ __launch_bounds__(256) void k_conv(const float* __restrict__ xin,
                                              const float* __restrict__ cw,
                                              const float* __restrict__ cb,
                                              float* __restrict__ xout) {
    int bid = blockIdx.x;
    int hh   = bid & 1;
    int wblk = (bid >> 1) & 15;
    int dblk = (bid >> 5) & 3;
    int b    = bid >> 7;
    int tid = threadIdx.x;
    int d = dblk * 64 + (tid & 63);
    int w = wblk * 4 + (tid >> 6);
    const float* inb = xin + (size_t)b * LL * DI + d;
    float* outb = xout + (size_t)b * LL * DI + d;
    float wg[9];
    #pragma unroll
    for (int i = 0; i < 9; ++i) wg[i] = cw[d * 9 + i];
    float bias = cb[d];
    #define LDV(hhh, www) ((((www) >= 0) && ((www) < Wn)) ? inb[(size_t)((hhh) * Wn + (www)) * DI] : 0.f)
    int hs = hh * 32;
    float r0[3], r1[3], r2[3];
    if (hs == 0) { r0[0] = r0[1] = r0[2] = 0.f; }
    else { r0[0] = LDV(hs - 1, w - 1); r0[1] = LDV(hs - 1, w); r0[2] = LDV(hs - 1, w + 1); }
    r1[0] = LDV(hs, w - 1); r1[1] = LDV(hs, w); r1[2] = LDV(hs, w + 1);
    r2[0] = LDV(hs + 1, w - 1); r2[1] = LDV(hs + 1, w); r2[2] = LDV(hs + 1, w + 1);
    for (int h = hs; h < hs + 32; ++h) {
        float acc = bias + wg[0] * r0[0] + wg[1] * r0[1] + wg[2] * r0[2]
                         + wg[3] * r1[0] + wg[4] * r1[1] + wg[5] * r1[2]
                         + wg[6] * r2[0] + wg[7] * r2[1] + wg[8] * r2[2];
        float sig = 1.f / (1.f + __expf(-acc));
        outb[(size_t)(h * Wn + w) * DI] = acc * sig;
        r0[0] = r1[0]; r0[1] = r1[1]; r0[2] = r1[2];
        r1[0] = r2[0]; r1[1] = r2[1]; r1[2] = r2[2];
        if (h + 2 < Hn) { r2[0] = LDV(h + 2, w - 1); r2[1] = LDV(h + 2, w); r2[2] = LDV(h + 2, w + 1); }
        else { r2[0] = r2[1] = r2[2] = 0.f; }
    }
    #undef LDV
}

// ---------- kernel 3: projection GEMM (gather-free, all 4 directions at once) ----------
// P[(b*LL+pos)*160 + k*40 + c] = sum_d xpw[k*40+c][d] * xcS[b,pos,d]
// grid 256 = 4b * 64 rowtiles(64) ; block 512 = 16 rt(4 rows) x 32 ct(5 cols)
__global__ __launch_bounds__(512) void k_proj(const float* __restrict__ xcS,
                                              const float* __restrict__ xpw,
                                              float* __restrict__ P) {
    __shared__ float sX[32][68];    // [kk][row]
    __shared__ float sW[32][164];   // [kk][c]
    int bid = blockIdx.x;
    int r0 = (bid & 63) * 64;
    int b = bid >> 6;
    int tid = threadIdx.x;
    int ct = tid & 31;   // cols c0 = ct*5
    int rt = tid >> 5;   // rows r = rt*4 .. +3
    float acc[4][5] = {};
    const float* Xb = xcS + ((size_t)b * LL + r0) * DI;
    for (int k0 = 0; k0 < DI; k0 += 32) {
        {
            int row = tid >> 3, k4 = tid & 7;     // 512 float4 = 64 rows x 32 kk
            float4 v = *(const float4*)(Xb + (size_t)row * DI + k0 + k4 * 4);
            sX[k4 * 4 + 0][row] = v.x; sX[k4 * 4 + 1][row] = v.y;
            sX[k4 * 4 + 2][row] = v.z; sX[k4 * 4 + 3][row] = v.w;
        }
        for (int i = tid; i < 1280; i += 512) {   // 160 c x 32 kk
            int c = i >> 3, k4 = i & 7;
            float4 v = *(const float4*)(xpw + (size_t)c * DI + k0 + k4 * 4);
            sW[k4 * 4 + 0][c] = v.x; sW[k4 * 4 + 1][c] = v.y;
            sW[k4 * 4 + 2][c] = v.z; sW[k4 * 4 + 3][c] = v.w;
        }
        __syncthreads();
        #pragma unroll 4
        for (int kk = 0; kk < 32; ++kk) {
            float4 xv = *(const float4*)&sX[kk][rt * 4];
            float xa[4] = {xv.x, xv.y, xv.z, xv.w};
            float wa[5];
            #pragma unroll
            for (int j = 0; j < 5; ++j) wa[j] = sW[kk][ct * 5 + j];
            #pragma unroll
            for (int i = 0; i < 4; ++i)
                #pragma unroll
                for (int j = 0; j < 5; ++j) acc[i][j] += xa[i] * wa[j];
        }
        __syncthreads();
    }
    float* ob = P + ((size_t)b * LL + r0 + rt * 4) * 160 + ct * 5;
    #pragma unroll
    for (int i = 0; i < 4; ++i)
        #pragma unroll
        for (int j = 0; j < 5; ++j) ob[(size_t)i * 160 + j] = acc[i][j];
}

// ---------- scan common: load per-(k,d) constants ----------
__device__ __forceinline__ void scan_consts(const float* __restrict__ A_logs,
                                            const float* __restrict__ dtw,
                                            int kd, float Ac[16], float wr[8], bool& chainable) {
    #pragma unroll
    for (int i = 0; i < 4; ++i) {
        float4 v = *(const float4*)(A_logs + (size_t)kd * 16 + i * 4);
        Ac[i * 4 + 0] = -__expf(v.x); Ac[i * 4 + 1] = -__expf(v.y);
        Ac[i * 4 + 2] = -__expf(v.z); Ac[i * 4 + 3] = -__expf(v.w);
    }
    float4 v0 = *(const float4*)(dtw + (size_t)kd * 8);
    float4 v1 = *(const float4*)(dtw + (size_t)kd * 8 + 4);
    wr[0] = v0.x; wr[1] = v0.y; wr[2] = v0.z; wr[3] = v0.w;
    wr[4] = v1.x; wr[5] = v1.y; wr[6] = v1.z; wr[7] = v1.w;
    // chainable iff Ac[n] == (n+1)*Ac[0] and Ac[0] == -1  (true for A_logs=log(1..16))
    chainable = fabsf(Ac[0] + 1.f) < 1e-6f;
    #pragma unroll
    for (int n = 1; n < 16; ++n)
        chainable = chainable && (fabsf(Ac[n] - (float)(n + 1) * Ac[0]) <= 1e-4f * fabsf(Ac[n]));
}

// softplus pieces: de = softplus(dtv), e1 = exp(-de) (exact identity: 1/(1+exp(dtv)))
__device__ __forceinline__ void softplus_e1(float dtv, float& de, float& e1) {
    if (dtv > 20.f) { de = dtv; e1 = __expf(-dtv); }
    else {
        float E = __expf(dtv);
        de = __logf(1.f + E);
        e1 = __builtin_amdgcn_rcpf(1.f + E);
    }
}

// ---------- kernel 4: scan phase 1 — per-chunk local scan, emit sde + h_end(bf16) ----------
// grid 2048 = 4b*4k*128c ; block 256 (thread = d)
__global__ __launch_bounds__(256) void k_scan1(const float* __restrict__ xcS,
                                               const float* __restrict__ P,
                                               const float* __restrict__ dtw,
                                               const float* __restrict__ dtb,
                                               const float* __restrict__ A_logs,
                                               float* __restrict__ carrG,
                                               unsigned short* __restrict__ carrH) {
    int bid = blockIdx.x;
    int c = bid & (NC - 1);
    int k = (bid >> 7) & 3;
    int b = bid >> 9;
    int d = threadIdx.x;
    int kd = k * DI + d;
    float Ac[16], wr[8];
    bool chainable;
    scan_consts(A_logs, dtw, kd, Ac, wr, chainable);
    float bias = dtb[kd];
    float h[16];
    #pragma unroll
    for (int n = 0; n < 16; ++n) h[n] = 0.f;
    float sde = 0.f;
    const float* xb = xcS + (size_t)b * LL * DI;
    const float* Pb = P + (size_t)b * LL * 160 + k * 40;
    int t0 = c * CHUNK;
    if (chainable) {
        for (int tt = 0; tt < CHUNK; ++tt) {
            int t = t0 + tt;
            int pos = posk(k, t);
            const float* rec = Pb + (size_t)pos * 160;
            float4 q0 = *(const float4*)rec;
            float4 q1 = *(const float4*)(rec + 4);
            float dtv = bias + wr[0] * q0.x + wr[1] * q0.y + wr[2] * q0.z + wr[3] * q0.w
                             + wr[4] * q1.x + wr[5] * q1.y + wr[6] * q1.z + wr[7] * q1.w;
            float de, e1;
            softplus_e1(dtv, de, e1);
            float u = xb[(size_t)pos * DI + d];
            float du = de * u;
            sde += de;
            float Ba[16];
            #pragma unroll
            for (int i = 0; i < 4; ++i) {
                float4 v = *(const float4*)(rec + 8 + i * 4);
                Ba[i * 4 + 0] = v.x; Ba[i * 4 + 1] = v.y; Ba[i * 4 + 2] = v.z; Ba[i * 4 + 3] = v.w;
            }
            float en = e1;
            #pragma unroll
            for (int n = 0; n < 16; ++n) {
                h[n] = en * h[n] + du * Ba[n];
                en *= e1;
            }
        }
    } else {
        for (int tt = 0; tt < CHUNK; ++tt) {
            int t = t0 + tt;
            int pos = posk(k, t);
            const float* rec = Pb + (size_t)pos * 160;
            float4 q0 = *(const float4*)rec;
            float4 q1 = *(const float4*)(rec + 4);
            float dtv = bias + wr[0] * q0.x + wr[1] * q0.y + wr[2] * q0.z + wr[3] * q0.w
                             + wr[4] * q1.x + wr[5] * q1.y + wr[6] * q1.z + wr[7] * q1.w;
            float de = softplus_f(dtv);
            float u = xb[(size_t)pos * DI + d];
            float du = de * u;
            sde += de;
            float Ba[16];
            #pragma unroll
            for (int i = 0; i < 4; ++i) {
                float4 v = *(const float4*)(rec + 8 + i * 4);
                Ba[i * 4 + 0] = v.x; Ba[i * 4 + 1] = v.y; Ba[i * 4 + 2] = v.z; Ba[i * 4 + 3] = v.w;
            }
            #pragma unroll
            for (int n = 0; n < 16; ++n)
                h[n] = __expf(de * Ac[n]) * h[n] + du * Ba[n];
        }
    }
    carrG[((size_t)(b * Kn + k) * NC + c) * DI + d] = sde;
    size_t hbase = ((size_t)(b * Kn + k) * NC + c) * 16 * DI + d;
    #pragma unroll
    for (int n = 0; n < 16; ++n)
        carrH[hbase + (size_t)n * DI] = f2bf(h[n]);
}

// ---------- kernel 5: scan phase 2 — combine carries across chunks ----------
// grid 256 ; block 256 ; thread = (bk,n,d); a_c recomputed as exp(Ac*sde_c)
__global__ __launch_bounds__(256) void k_scan2(const float* __restrict__ carrG,
                                               const float* __restrict__ A_logs,
                                               unsigned short* __restrict__ carrH) {
    int gid = blockIdx.x * 256 + threadIdx.x;
    int d = gid & 255;
    int n = (gid >> 8) & 15;
    int bk = gid >> 12;
    int k = bk & 3;
    float Ac = -__expf(A_logs[(size_t)(k * DI + d) * 16 + n]);
    size_t gbase = (size_t)bk * NC * DI + d;
    size_t hbase = ((size_t)bk * NC * 16 + n) * DI + d;
    const size_t hs = (size_t)16 * DI;
    float hr = 0.f;
    #pragma unroll
    for (int g = 0; g < NC / 32; ++g) {
        float sv[32];
        unsigned short hvv[32];
        #pragma unroll
        for (int j = 0; j < 32; ++j) sv[j] = carrG[gbase + (size_t)(g * 32 + j) * DI];
        #pragma unroll
        for (int j = 0; j < 32; ++j) hvv[j] = carrH[hbase + (size_t)(g * 32 + j) * hs];
        #pragma unroll
        for (int j = 0; j < 32; ++j) {
            float a = __expf(Ac * sv[j]);
            float he = bf2f(hvv[j]);
            carrH[hbase + (size_t)(g * 32 + j) * hs] = f2bf(hr);   // h_init for this chunk
            hr = a * hr + he;
        }
    }
}

// ---------- kernel 6: scan phase 3 — re-scan chunk from h_init, emit y ----------
// grid 2048 ; block 256 (thread = d)
__global__ __launch_bounds__(256) void k_scan3(const float* __restrict__ xcS,
                                               const float* __restrict__ P,
                                               const float* __restrict__ dtw,
                                               const float* __restrict__ dtb,
                                               const float* __restrict__ A_logs,
                                               const float* __restrict__ Ds,
                                               const unsigned short* __restrict__ carrH,
                                               float* __restrict__ y) {
    int bid = blockIdx.x;
    int c = bid & (NC - 1);
    int k = (bid >> 7) & 3;
    int b = bid >> 9;
    int d = threadIdx.x;
    int kd = k * DI + d;
    float Ac[16], wr[8];
    bool chainable;
    scan_consts(A_logs, dtw, kd, Ac, wr, chainable);
    float bias = dtb[kd];
    float Dv = Ds[kd];
    float h[16];
    size_t hbase = ((size_t)(b * Kn + k) * NC + c) * 16 * DI + d;
    #pragma unroll
    for (int n = 0; n < 16; ++n) h[n] = bf2f(carrH[hbase + (size_t)n * DI]);
    const float* xb = xcS + (size_t)b * LL * DI;
    const float* Pb = P + (size_t)b * LL * 160 + k * 40;
    float* yb = y + (size_t)b * LL * DI + d;
    int t0 = c * CHUNK;
    if (chainable) {
        for (int tt = 0; tt < CHUNK; ++tt) {
            int t = t0 + tt;
            int pos = posk(k, t);
            const float* rec = Pb + (size_t)pos * 160;
            float4 q0 = *(const float4*)rec;
            float4 q1 = *(const float4*)(rec + 4);
            float dtv = bias + wr[0] * q0.x + wr[1] * q0.y + wr[2] * q0.z + wr[3] * q0.w
                             + wr[4] * q1.x + wr[5] * q1.y + wr[6] * q1.z + wr[7] * q1.w;
            float de, e1;
            softplus_e1(dtv, de, e1);
            float u = xb[(size_t)pos * DI + d];
            float du = de * u;
            float Ba[16], Ca[16];
            #pragma unroll
            for (int i = 0; i < 4; ++i) {
                float4 v = *(const float4*)(rec + 8 + i * 4);
                Ba[i * 4 + 0] = v.x; Ba[i * 4 + 1] = v.y; Ba[i * 4 + 2] = v.z; Ba[i * 4 + 3] = v.w;
                float4 w = *(const float4*)(rec + 24 + i * 4);
                Ca[i * 4 + 0] = w.x; Ca[i * 4 + 1] = w.y; Ca[i * 4 + 2] = w.z; Ca[i * 4 + 3] = w.w;
            }
            float yv = Dv * u;
            float en = e1;
            #pragma unroll
            for (int n = 0; n < 16; ++n) {
                h[n] = en * h[n] + du * Ba[n];
                yv += h[n] * Ca[n];
                en *= e1;
            }
            atomicAdd(yb + (size_t)pos * DI, yv);
        }
    } else {
        for (int tt = 0; tt < CHUNK; ++tt) {
            int t = t0 + tt;
            int pos = posk(k, t);
            const float* rec = Pb + (size_t)pos * 160;
            float4 q0 = *(const float4*)rec;
            float4 q1 = *(const float4*)(rec + 4);
            float dtv = bias + wr[0] * q0.x + wr[1] * q0.y + wr[2] * q0.z + wr[3] * q0.w
                             + wr[4] * q1.x + wr[5] * q1.y + wr[6] * q1.z + wr[7] * q1.w;
            float de = softplus_f(dtv);
            float u = xb[(size_t)pos * DI + d];
            float du = de * u;
            float Ba[16], Ca[16];
            #pragma unroll
            for (int i = 0; i < 4; ++i) {
                float4 v = *(const float4*)(rec + 8 + i * 4);
                Ba[i * 4 + 0] = v.x; Ba[i * 4 + 1] = v.y; Ba[i * 4 + 2] = v.z; Ba[i * 4 + 3] = v.w;
                float4 w = *(const float4*)(rec + 24 + i * 4);
                Ca[i * 4 + 0] = w.x; Ca[i * 4 + 1] = w.y; Ca[i * 4 + 2] = w.z; Ca[i * 4 + 3] = w.w;
            }
            float yv = Dv * u;
            #pragma unroll
            for (int n = 0; n < 16; ++n) {
                h[n] = __expf(de * Ac[n]) * h[n] + du * Ba[n];
                yv += h[n] * Ca[n];
            }
            atomicAdd(yb + (size_t)pos * DI, yv);
        }
    }
}

// ---------- kernel 7: LayerNorm over last dim (in-place on d_out) ----------
// grid 16384 rows ; block 256
__global__ __launch_bounds__(256) void k_ln(float* __restrict__ y,
                                            const float* __restrict__ gamma,
                                            const float* __restrict__ beta) {
    __shared__ float s1[4], s2[4];
    int r = blockIdx.x;
    int tid = threadIdx.x;
    float v = y[(size_t)r * DI + tid];
    float a = v, bsq = v * v;
    #pragma unroll
    for (int off = 32; off; off >>= 1) {
        a += __shfl_xor(a, off);
        bsq += __shfl_xor(bsq, off);
    }
    if ((tid & 63) == 0) { s1[tid >> 6] = a; s2[tid >> 6] = bsq; }
    __syncthreads();
    float S1 = s1[0] + s1[1] + s1[2] + s1[3];
    float S2 = s2[0] + s2[1] + s2[2] + s2[3];
    float mu = S1 * (1.f / 256.f);
    float var = S2 * (1.f / 256.f) - mu * mu;
    float rs = rsqrtf(var + 1e-5f);
    y[(size_t)r * DI + tid] = (v - mu) * rs * gamma[tid] + beta[tid];
}

// ---------- launch ----------
extern "C" void kernel_launch(void* const* d_in, const int* in_sizes, int n_in,
                              void* d_out, int out_size, void* d_ws, size_t ws_size,
                              hipStream_t stream) {
    const float* x    = (const float*)d_in[0];
    const float* ipw  = (const float*)d_in[1];
    const float* cw   = (const float*)d_in[2];
    const float* cb   = (const float*)d_in[3];
    const float* xpw  = (const float*)d_in[4];
    const float* dtw  = (const float*)d_in[5];
    const float* dtb  = (const float*)d_in[6];
    const float* alog = (const float*)d_in[7];
    const float* Ds   = (const float*)d_in[8];
    const float* gam  = (const float*)d_in[9];
    const float* bet  = (const float*)d_in[10];

    // ws layout (bytes):
    //   [0, 16777216)           carrH (bf16 B*K*NC*16*DI)  -- aliases xls_pre (in_proj out, dead after conv)
    //   [16777216, 18874368)    carrG (fp32 B*K*NC*DI, per-chunk sum of delta)
    //   [18874368, 35651584)    xcS   (fp32 B*L*DI, channel-last conv+SiLU output)
    //   [35651584, 46137344)    P     (fp32 B*L*160 projection records, image order: [k*40: dts|B|C])
    const size_t WS_NEED = 46137344;
    if (ws_size < WS_NEED) return;

    char* ws = (char*)d_ws;
    unsigned short* carrH = (unsigned short*)(ws + 0);
    float* carrG   = (float*)(ws + 16777216);
    float* xls_pre = (float*)(ws + 0);           // alias over carrH/carrG (dead before scan1)
    float* xcS     = (float*)(ws + 18874368);
    float* P       = (float*)(ws + 35651584);
    float* y       = (float*)d_out;

    hipMemsetAsync(d_out, 0, (size_t)out_size * sizeof(float), stream);
    k_inproj<<<1024,  256, 0, stream>>>(x, ipw, xls_pre);
    k_conv  <<<512,   256, 0, stream>>>(xls_pre, cw, cb, xcS);
    k_proj  <<<256,   512, 0, stream>>>(xcS, xpw, P);
    k_scan1 <<<2048,  256, 0, stream>>>(xcS, P, dtw, dtb, alog, carrG, carrH);
    k_scan2 <<<256,   256, 0, stream>>>(carrG, alog, carrH);
    k_scan3 <<<2048,  256, 0, stream>>>(xcS, P, dtw, dtb, alog, Ds, carrH, y);
    k_ln    <<<16384, 256, 0, stream>>>(y, gam, bet);
}

// Round 6
// 262.260 us; speedup vs baseline: 4.2907x; 1.0867x over previous
//
#include <hip/hip_runtime.h>

constexpr int Bn = 4;
constexpr int Hn = 64;
constexpr int Wn = 64;
constexpr int LL = Hn * Wn;     // 4096
constexpr int DM = 128;
constexpr int DI = 256;
constexpr int Nn = 16;
constexpr int Rn = 8;
constexpr int Kn = 4;
constexpr int NC = 128;         // chunks per (b,k) scan
constexpr int CHUNK = LL / NC;  // 32

using bf16x8 = __attribute__((ext_vector_type(8))) short;
using f32x4  = __attribute__((ext_vector_type(4))) float;

// ---------- helpers ----------
__device__ __forceinline__ float bf2f(unsigned short s) {
    return __uint_as_float(((unsigned int)s) << 16);
}
__device__ __forceinline__ unsigned short f2bf(float f) {
    unsigned int u = __float_as_uint(f);
    u += 0x7FFFu + ((u >> 16) & 1u);   // RNE
    return (unsigned short)(u >> 16);
}
__device__ __forceinline__ float softplus_f(float x) {
    if (x > 20.f) return x;
    return __logf(1.f + __expf(x));
}
// scan-order index t -> image position (row-major h*64+w)
__device__ __forceinline__ int posk(int k, int t) {
    int q = (k >= 2) ? (LL - 1 - t) : t;
    return (k & 1) ? (((q & 63) << 6) | (q >> 6)) : q;
}

// ---------- kernel 1: in_proj GEMM via MFMA bf16 ----------
// out[row][d] = sum_c x[row][c]*W[d][c], M=16384 N=256 K=128
// grid 256 (64-row tiles) ; block 256 = 4 waves; wave w does rows w*16..+15, all 256 cols
__global__ __launch_bounds__(256) void k_inproj(const float* __restrict__ x,
                                                const float* __restrict__ wp,
                                                float* __restrict__ out) {
    __shared__ short sA[64][40];    // [m][k] bf16, stride 40 (80B) for bank spread
    __shared__ short sW[256][40];   // [n][k] bf16
    int r0 = blockIdx.x * 64;
    int tid = threadIdx.x;
    int w = tid >> 6, lane = tid & 63;
    int ln15 = lane & 15, q8 = (lane >> 4) * 8;
    f32x4 acc[16];
    #pragma unroll
    for (int i = 0; i < 16; ++i) acc[i] = f32x4{0.f, 0.f, 0.f, 0.f};
    for (int kk = 0; kk < 4; ++kk) {
        // stage A: 64 rows x 32 k  (thread: row=tid>>2, c0=(tid&3)*8)
        {
            int r = tid >> 2, c0 = (tid & 3) * 8;
            const float* src = x + (size_t)(r0 + r) * DM + kk * 32 + c0;
            float4 v0 = *(const float4*)src;
            float4 v1 = *(const float4*)(src + 4);
            bf16x8 s;
            s[0] = (short)f2bf(v0.x); s[1] = (short)f2bf(v0.y);
            s[2] = (short)f2bf(v0.z); s[3] = (short)f2bf(v0.w);
            s[4] = (short)f2bf(v1.x); s[5] = (short)f2bf(v1.y);
            s[6] = (short)f2bf(v1.z); s[7] = (short)f2bf(v1.w);
            *(bf16x8*)&sA[r][c0] = s;
        }
        // stage W: 256 rows x 32 k (thread: row=tid)
        {
            const float* src = wp + (size_t)tid * DM + kk * 32;
            #pragma unroll
            for (int j = 0; j < 8; ++j) {
                float4 v = *(const float4*)(src + j * 4);
                sW[tid][j * 4 + 0] = (short)f2bf(v.x);
                sW[tid][j * 4 + 1] = (short)f2bf(v.y);
                sW[tid][j * 4 + 2] = (short)f2bf(v.z);
                sW[tid][j * 4 + 3] = (short)f2bf(v.w);
            }
        }
        __syncthreads();
        bf16x8 a = *(bf16x8*)&sA[w * 16 + ln15][q8];
        #pragma unroll
        for (int ni = 0; ni < 16; ++ni) {
            bf16x8 bfr = *(bf16x8*)&sW[ni * 16 + ln15][q8];
            acc[ni] = __builtin_amdgcn_mfma_f32_16x16x32_bf16(a, bfr, acc[ni], 0, 0, 0);
        }
        __syncthreads();
    }
    // store: D frag: col = ni*16 + ln15, row = w*16 + (lane>>4)*4 + r
    int rbase = r0 + w * 16 + (lane >> 4) * 4;
    #pragma unroll
    for (int ni = 0; ni < 16; ++ni)
        #pragma unroll
        for (int r = 0; r < 4; ++r)
            out[(size_t)(rbase + r) * DI + ni * 16 + ln15] = acc[ni][r];
}

// ---------- kernel 2: depthwise 3x3 conv + bias + SiLU, channel-last; emits fp32 + bf16 ----------
// grid 512 = 4b * 4dblk * 16wblk * 2hhalf ; block 256 = 64 d-lanes * 4 w
__global__ __launch_bounds__(256) void k_conv(const float* __restrict__ xin,
                                              const float* __restrict__ cw,
                                              const float* __restrict__ cb,
                                              float* __restrict__ xout,
                                              unsigned short* __restrict__ xoutB) {
    int bid = blockIdx.x;
    int hh   = bid & 1;
    int wblk = (bid >> 1) & 15;
    int dblk = (bid >> 5) & 3;
    int b    = bid >> 7;
    int tid = threadIdx.x;
    int d = dblk * 64 + (tid & 63);
    int w = wblk * 4 + (tid >> 6);
    const float* inb = xin + (size_t)b * LL * DI + d;
    float* outb = xout + (size_t)b * LL * DI + d;
    unsigned short* outbB = xoutB + (size_t)b * LL * DI + d;
    float wg[9];
    #pragma unroll
    for (int i = 0; i < 9; ++i) wg[i] = cw[d * 9 + i];
    float bias = cb[d];
    #define LDV(hhh, www) ((((www) >= 0) && ((www) < Wn)) ? inb[(size_t)((hhh) * Wn + (www)) * DI] : 0.f)
    int hs = hh * 32;
    float r0[3], r1[3], r2[3];
    if (hs == 0) { r0[0] = r0[1] = r0[2] = 0.f; }
    else { r0[0] = LDV(hs - 1, w - 1); r0[1] = LDV(hs - 1, w); r0[2] = LDV(hs - 1, w + 1); }
    r1[0] = LDV(hs, w - 1); r1[1] = LDV(hs, w); r1[2] = LDV(hs, w + 1);
    r2[0] = LDV(hs + 1, w - 1); r2[1] = LDV(hs + 1, w); r2[2] = LDV(hs + 1, w + 1);
    for (int h = hs; h < hs + 32; ++h) {
        float acc = bias + wg[0] * r0[0] + wg[1] * r0[1] + wg[2] * r0[2]
                         + wg[3] * r1[0] + wg[4] * r1[1] + wg[5] * r1[2]
                         + wg[6] * r2[0] + wg[7] * r2[1] + wg[8] * r2[2];
        float sig = 1.f / (1.f + __expf(-acc));
        float val = acc * sig;
        outb[(size_t)(h * Wn + w) * DI] = val;
        outbB[(size_t)(h * Wn + w) * DI] = f2bf(val);
        r0[0] = r1[0]; r0[1] = r1[1]; r0[2] = r1[2];
        r1[0] = r2[0]; r1[1] = r2[1]; r1[2] = r2[2];
        if (h + 2 < Hn) { r2[0] = LDV(h + 2, w - 1); r2[1] = LDV(h + 2, w); r2[2] = LDV(h + 2, w + 1); }
        else { r2[0] = r2[1] = r2[2] = 0.f; }
    }
    #undef LDV
}

// ---------- kernel 3: projection GEMM via MFMA bf16 ----------
// P[row][c] = sum_d xpw[c][d]*xcB[row][d], M=16384 N=160 K=256
// grid 256 (64-row tiles) ; block 256 = 4 waves; wave w: rows w*16..+15, cols 0..159
__global__ __launch_bounds__(256) void k_proj(const unsigned short* __restrict__ xcB,
                                              const float* __restrict__ xpw,
                                              float* __restrict__ P) {
    __shared__ short sA[64][40];    // [m][k] bf16
    __shared__ short sW[160][40];   // [n][k] bf16
    int r0 = blockIdx.x * 64;
    int tid = threadIdx.x;
    int w = tid >> 6, lane = tid & 63;
    int ln15 = lane & 15, q8 = (lane >> 4) * 8;
    f32x4 acc[10];
    #pragma unroll
    for (int i = 0; i < 10; ++i) acc[i] = f32x4{0.f, 0.f, 0.f, 0.f};
    for (int kk = 0; kk < 8; ++kk) {
        // stage A: 64 rows x 32 k bf16 (direct copy)
        {
            int r = tid >> 2, c0 = (tid & 3) * 8;
            *(bf16x8*)&sA[r][c0] =
                *(const bf16x8*)(xcB + (size_t)(r0 + r) * DI + kk * 32 + c0);
        }
        // stage W: 160 rows x 32 k (thread t<160: row t)
        if (tid < 160) {
            const float* src = xpw + (size_t)tid * DI + kk * 32;
            #pragma unroll
            for (int j = 0; j < 8; ++j) {
                float4 v = *(const float4*)(src + j * 4);
                sW[tid][j * 4 + 0] = (short)f2bf(v.x);
                sW[tid][j * 4 + 1] = (short)f2bf(v.y);
                sW[tid][j * 4 + 2] = (short)f2bf(v.z);
                sW[tid][j * 4 + 3] = (short)f2bf(v.w);
            }
        }
        __syncthreads();
        bf16x8 a = *(bf16x8*)&sA[w * 16 + ln15][q8];
        #pragma unroll
        for (int ni = 0; ni < 10; ++ni) {
            bf16x8 bfr = *(bf16x8*)&sW[ni * 16 + ln15][q8];
            acc[ni] = __builtin_amdgcn_mfma_f32_16x16x32_bf16(a, bfr, acc[ni], 0, 0, 0);
        }
        __syncthreads();
    }
    int rbase = r0 + w * 16 + (lane >> 4) * 4;
    #pragma unroll
    for (int ni = 0; ni < 10; ++ni)
        #pragma unroll
        for (int r = 0; r < 4; ++r)
            P[(size_t)(rbase + r) * 160 + ni * 16 + ln15] = acc[ni][r];
}

// ---------- scan common: load per-(k,d) constants ----------
__device__ __forceinline__ void scan_consts(const float* __restrict__ A_logs,
                                            const float* __restrict__ dtw,
                                            int kd, float Ac[16], float wr[8], bool& chainable) {
    #pragma unroll
    for (int i = 0; i < 4; ++i) {
        float4 v = *(const float4*)(A_logs + (size_t)kd * 16 + i * 4);
        Ac[i * 4 + 0] = -__expf(v.x); Ac[i * 4 + 1] = -__expf(v.y);
        Ac[i * 4 + 2] = -__expf(v.z); Ac[i * 4 + 3] = -__expf(v.w);
    }
    float4 v0 = *(const float4*)(dtw + (size_t)kd * 8);
    float4 v1 = *(const float4*)(dtw + (size_t)kd * 8 + 4);
    wr[0] = v0.x; wr[1] = v0.y; wr[2] = v0.z; wr[3] = v0.w;
    wr[4] = v1.x; wr[5] = v1.y; wr[6] = v1.z; wr[7] = v1.w;
    // chainable iff Ac[n] == (n+1)*Ac[0] and Ac[0] == -1  (true for A_logs=log(1..16))
    chainable = fabsf(Ac[0] + 1.f) < 1e-6f;
    #pragma unroll
    for (int n = 1; n < 16; ++n)
        chainable = chainable && (fabsf(Ac[n] - (float)(n + 1) * Ac[0]) <= 1e-4f * fabsf(Ac[n]));
}

// softplus pieces: de = softplus(dtv), e1 = exp(-de) (exact identity: 1/(1+exp(dtv)))
__device__ __forceinline__ void softplus_e1(float dtv, float& de, float& e1) {
    if (dtv > 20.f) { de = dtv; e1 = __expf(-dtv); }
    else {
        float E = __expf(dtv);
        de = __logf(1.f + E);
        e1 = __builtin_amdgcn_rcpf(1.f + E);
    }
}

// ---------- kernel 4: scan phase 1 — per-chunk local scan, emit sde + h_end(bf16) ----------
// grid 2048 = 4b*4k*128c ; block 256 (thread = d)
__global__ __launch_bounds__(256) void k_scan1(const float* __restrict__ xcS,
                                               const float* __restrict__ P,
                                               const float* __restrict__ dtw,
                                               const float* __restrict__ dtb,
                                               const float* __restrict__ A_logs,
                                               float* __restrict__ carrG,
                                               unsigned short* __restrict__ carrH) {
    int bid = blockIdx.x;
    int c = bid & (NC - 1);
    int k = (bid >> 7) & 3;
    int b = bid >> 9;
    int d = threadIdx.x;
    int kd = k * DI + d;
    float Ac[16], wr[8];
    bool chainable;
    scan_consts(A_logs, dtw, kd, Ac, wr, chainable);
    float bias = dtb[kd];
    float h[16];
    #pragma unroll
    for (int n = 0; n < 16; ++n) h[n] = 0.f;
    float sde = 0.f;
    const float* xb = xcS + (size_t)b * LL * DI;
    const float* Pb = P + (size_t)b * LL * 160 + k * 40;
    int t0 = c * CHUNK;
    if (chainable) {
        for (int tt = 0; tt < CHUNK; ++tt) {
            int t = t0 + tt;
            int pos = posk(k, t);
            const float* rec = Pb + (size_t)pos * 160;
            float4 q0 = *(const float4*)rec;
            float4 q1 = *(const float4*)(rec + 4);
            float dtv = bias + wr[0] * q0.x + wr[1] * q0.y + wr[2] * q0.z + wr[3] * q0.w
                             + wr[4] * q1.x + wr[5] * q1.y + wr[6] * q1.z + wr[7] * q1.w;
            float de, e1;
            softplus_e1(dtv, de, e1);
            float u = xb[(size_t)pos * DI + d];
            float du = de * u;
            sde += de;
            float Ba[16];
            #pragma unroll
            for (int i = 0; i < 4; ++i) {
                float4 v = *(const float4*)(rec + 8 + i * 4);
                Ba[i * 4 + 0] = v.x; Ba[i * 4 + 1] = v.y; Ba[i * 4 + 2] = v.z; Ba[i * 4 + 3] = v.w;
            }
            float en = e1;
            #pragma unroll
            for (int n = 0; n < 16; ++n) {
                h[n] = en * h[n] + du * Ba[n];
                en *= e1;
            }
        }
    } else {
        for (int tt = 0; tt < CHUNK; ++tt) {
            int t = t0 + tt;
            int pos = posk(k, t);
            const float* rec = Pb + (size_t)pos * 160;
            float4 q0 = *(const float4*)rec;
            float4 q1 = *(const float4*)(rec + 4);
            float dtv = bias + wr[0] * q0.x + wr[1] * q0.y + wr[2] * q0.z + wr[3] * q0.w
                             + wr[4] * q1.x + wr[5] * q1.y + wr[6] * q1.z + wr[7] * q1.w;
            float de = softplus_f(dtv);
            float u = xb[(size_t)pos * DI + d];
            float du = de * u;
            sde += de;
            float Ba[16];
            #pragma unroll
            for (int i = 0; i < 4; ++i) {
                float4 v = *(const float4*)(rec + 8 + i * 4);
                Ba[i * 4 + 0] = v.x; Ba[i * 4 + 1] = v.y; Ba[i * 4 + 2] = v.z; Ba[i * 4 + 3] = v.w;
            }
            #pragma unroll
            for (int n = 0; n < 16; ++n)
                h[n] = __expf(de * Ac[n]) * h[n] + du * Ba[n];
        }
    }
    carrG[((size_t)(b * Kn + k) * NC + c) * DI + d] = sde;
    size_t hbase = ((size_t)(b * Kn + k) * NC + c) * 16 * DI + d;
    #pragma unroll
    for (int n = 0; n < 16; ++n)
        carrH[hbase + (size_t)n * DI] = f2bf(h[n]);
}

// ---------- kernel 5: scan phase 2 — combine carries across chunks ----------
// grid 256 ; block 256 ; thread = (bk,n,d); a_c recomputed as exp(Ac*sde_c)
__global__ __launch_bounds__(256) void k_scan2(const float* __restrict__ carrG,
                                               const float* __restrict__ A_logs,
                                               unsigned short* __restrict__ carrH) {
    int gid = blockIdx.x * 256 + threadIdx.x;
    int d = gid & 255;
    int n = (gid >> 8) & 15;
    int bk = gid >> 12;
    int k = bk & 3;
    float Ac = -__expf(A_logs[(size_t)(k * DI + d) * 16 + n]);
    size_t gbase = (size_t)bk * NC * DI + d;
    size_t hbase = ((size_t)bk * NC * 16 + n) * DI + d;
    const size_t hs = (size_t)16 * DI;
    float hr = 0.f;
    #pragma unroll
    for (int g = 0; g < NC / 32; ++g) {
        float sv[32];
        unsigned short hvv[32];
        #pragma unroll
        for (int j = 0; j < 32; ++j) sv[j] = carrG[gbase + (size_t)(g * 32 + j) * DI];
        #pragma unroll
        for (int j = 0; j < 32; ++j) hvv[j] = carrH[hbase + (size_t)(g * 32 + j) * hs];
        #pragma unroll
        for (int j = 0; j < 32; ++j) {
            float a = __expf(Ac * sv[j]);
            float he = bf2f(hvv[j]);
            carrH[hbase + (size_t)(g * 32 + j) * hs] = f2bf(hr);   // h_init for this chunk
            hr = a * hr + he;
        }
    }
}

// ---------- kernel 6: scan phase 3 — re-scan chunk from h_init, emit y ----------
// grid 2048 ; block 256 (thread = d)
__global__ __launch_bounds__(256) void k_scan3(const float* __restrict__ xcS,
                                               const float* __restrict__ P,
                                               const float* __restrict__ dtw,
                                               const float* __restrict__ dtb,
                                               const float* __restrict__ A_logs,
                                               const float* __restrict__ Ds,
                                               const unsigned short* __restrict__ carrH,
                                               float* __restrict__ y) {
    int bid = blockIdx.x;
    int c = bid & (NC - 1);
    int k = (bid >> 7) & 3;
    int b = bid >> 9;
    int d = threadIdx.x;
    int kd = k * DI + d;
    float Ac[16], wr[8];
    bool chainable;
    scan_consts(A_logs, dtw, kd, Ac, wr, chainable);
    float bias = dtb[kd];
    float Dv = Ds[kd];
    float h[16];
    size_t hbase = ((size_t)(b * Kn + k) * NC + c) * 16 * DI + d;
    #pragma unroll
    for (int n = 0; n < 16; ++n) h[n] = bf2f(carrH[hbase + (size_t)n * DI]);
    const float* xb = xcS + (size_t)b * LL * DI;
    const float* Pb = P + (size_t)b * LL * 160 + k * 40;
    float* yb = y + (size_t)b * LL * DI + d;
    int t0 = c * CHUNK;
    if (chainable) {
        for (int tt = 0; tt < CHUNK; ++tt) {
            int t = t0 + tt;
            int pos = posk(k, t);
            const float* rec = Pb + (size_t)pos * 160;
            float4 q0 = *(const float4*)rec;
            float4 q1 = *(const float4*)(rec + 4);
            float dtv = bias + wr[0] * q0.x + wr[1] * q0.y + wr[2] * q0.z + wr[3] * q0.w
                             + wr[4] * q1.x + wr[5] * q1.y + wr[6] * q1.z + wr[7] * q1.w;
            float de, e1;
            softplus_e1(dtv, de, e1);
            float u = xb[(size_t)pos * DI + d];
            float du = de * u;
            float Ba[16], Ca[16];
            #pragma unroll
            for (int i = 0; i < 4; ++i) {
                float4 v = *(const float4*)(rec + 8 + i * 4);
                Ba[i * 4 + 0] = v.x; Ba[i * 4 + 1] = v.y; Ba[i * 4 + 2] = v.z; Ba[i * 4 + 3] = v.w;
                float4 w = *(const float4*)(rec + 24 + i * 4);
                Ca[i * 4 + 0] = w.x; Ca[i * 4 + 1] = w.y; Ca[i * 4 + 2] = w.z; Ca[i * 4 + 3] = w.w;
            }
            float yv = Dv * u;
            float en = e1;
            #pragma unroll
            for (int n = 0; n < 16; ++n) {
                h[n] = en * h[n] + du * Ba[n];
                yv += h[n] * Ca[n];
                en *= e1;
            }
            atomicAdd(yb + (size_t)pos * DI, yv);
        }
    } else {
        for (int tt = 0; tt < CHUNK; ++tt) {
            int t = t0 + tt;
            int pos = posk(k, t);
            const float* rec = Pb + (size_t)pos * 160;
            float4 q0 = *(const float4*)rec;
            float4 q1 = *(const float4*)(rec + 4);
            float dtv = bias + wr[0] * q0.x + wr[1] * q0.y + wr[2] * q0.z + wr[3] * q0.w
                             + wr[4] * q1.x + wr[5] * q1.y + wr[6] * q1.z + wr[7] * q1.w;
            float de = softplus_f(dtv);
            float u = xb[(size_t)pos * DI + d];
            float du = de * u;
            float Ba[16], Ca[16];
            #pragma unroll
            for (int i = 0; i < 4; ++i) {
                float4 v = *(const float4*)(rec + 8 + i * 4);
                Ba[i * 4 + 0] = v.x; Ba[i * 4 + 1] = v.y; Ba[i * 4 + 2] = v.z; Ba[i * 4 + 3] = v.w;
                float4 w = *(const float4*)(rec + 24 + i * 4);
                Ca[i * 4 + 0] = w.x; Ca[i * 4 + 1] = w.y; Ca[i * 4 + 2] = w.z; Ca[i * 4 + 3] = w.w;
            }
            float yv = Dv * u;
            #pragma unroll
            for (int n = 0; n < 16; ++n) {
                h[n] = __expf(de * Ac[n]) * h[n] + du * Ba[n];
                yv += h[n] * Ca[n];
            }
            atomicAdd(yb + (size_t)pos * DI, yv);
        }
    }
}

// ---------- kernel 7: LayerNorm over last dim (in-place on d_out) ----------
// grid 16384 rows ; block 256
__global__ __launch_bounds__(256) void k_ln(float* __restrict__ y,
                                            const float* __restrict__ gamma,
                                            const float* __restrict__ beta) {
    __shared__ float s1[4], s2[4];
    int r = blockIdx.x;
    int tid = threadIdx.x;
    float v = y[(size_t)r * DI + tid];
    float a = v, bsq = v * v;
    #pragma unroll
    for (int off = 32; off; off >>= 1) {
        a += __shfl_xor(a, off);
        bsq += __shfl_xor(bsq, off);
    }
    if ((tid & 63) == 0) { s1[tid >> 6] = a; s2[tid >> 6] = bsq; }
    __syncthreads();
    float S1 = s1[0] + s1[1] + s1[2] + s1[3];
    float S2 = s2[0] + s2[1] + s2[2] + s2[3];
    float mu = S1 * (1.f / 256.f);
    float var = S2 * (1.f / 256.f) - mu * mu;
    float rs = rsqrtf(var + 1e-5f);
    y[(size_t)r * DI + tid] = (v - mu) * rs * gamma[tid] + beta[tid];
}

// ---------- launch ----------
extern "C" void kernel_launch(void* const* d_in, const int* in_sizes, int n_in,
                              void* d_out, int out_size, void* d_ws, size_t ws_size,
                              hipStream_t stream) {
    const float* x    = (const float*)d_in[0];
    const float* ipw  = (const float*)d_in[1];
    const float* cw   = (const float*)d_in[2];
    const float* cb   = (const float*)d_in[3];
    const float* xpw  = (const float*)d_in[4];
    const float* dtw  = (const float*)d_in[5];
    const float* dtb  = (const float*)d_in[6];
    const float* alog = (const float*)d_in[7];
    const float* Ds   = (const float*)d_in[8];
    const float* gam  = (const float*)d_in[9];
    const float* bet  = (const float*)d_in[10];

    // ws layout (bytes):
    //   [0, 16777216)           carrH (bf16 B*K*NC*16*DI)  -- aliases xls_pre (in_proj out, dead after conv)
    //   [16777216, 18874368)    carrG (fp32 B*K*NC*DI, per-chunk sum of delta)
    //   [18874368, 35651584)    xcS   (fp32 B*L*DI, channel-last conv+SiLU output)
    //   [35651584, 46137344)    P     (fp32 B*L*160 projection records, image order: [k*40: dts|B|C])
    //   [46137344, 54525952)    xcB   (bf16 B*L*DI, conv output copy for MFMA proj)
    const size_t WS_NEED = 54525952;
    if (ws_size < WS_NEED) return;

    char* ws = (char*)d_ws;
    unsigned short* carrH = (unsigned short*)(ws + 0);
    float* carrG   = (float*)(ws + 16777216);
    float* xls_pre = (float*)(ws + 0);           // alias over carrH (dead before scan1)
    float* xcS     = (float*)(ws + 18874368);
    float* P       = (float*)(ws + 35651584);
    unsigned short* xcB = (unsigned short*)(ws + 46137344);
    float* y       = (float*)d_out;

    hipMemsetAsync(d_out, 0, (size_t)out_size * sizeof(float), stream);
    k_inproj<<<256,   256, 0, stream>>>(x, ipw, xls_pre);
    k_conv  <<<512,   256, 0, stream>>>(xls_pre, cw, cb, xcS, xcB);
    k_proj  <<<256,   256, 0, stream>>>(xcB, xpw, P);
    k_scan1 <<<2048,  256, 0, stream>>>(xcS, P, dtw, dtb, alog, carrG, carrH);
    k_scan2 <<<256,   256, 0, stream>>>(carrG, alog, carrH);
    k_scan3 <<<2048,  256, 0, stream>>>(xcS, P, dtw, dtb, alog, Ds, carrH, y);
    k_ln    <<<16384, 256, 0, stream>>>(y, gam, bet);
}

// Round 7
// 246.873 us; speedup vs baseline: 4.5581x; 1.0623x over previous
//
#include <hip/hip_runtime.h>

constexpr int Bn = 4;
constexpr int Hn = 64;
constexpr int Wn = 64;
constexpr int LL = Hn * Wn;     // 4096
constexpr int DM = 128;
constexpr int DI = 256;
constexpr int Nn = 16;
constexpr int Rn = 8;
constexpr int Kn = 4;
constexpr int NC = 128;         // chunks per (b,k) scan
constexpr int CHUNK = LL / NC;  // 32

using bf16x8 = __attribute__((ext_vector_type(8))) short;
using f32x4  = __attribute__((ext_vector_type(4))) float;

// ---------- helpers ----------
__device__ __forceinline__ float bf2f(unsigned short s) {
    return __uint_as_float(((unsigned int)s) << 16);
}
__device__ __forceinline__ unsigned short f2bf(float f) {
    unsigned int u = __float_as_uint(f);
    u += 0x7FFFu + ((u >> 16) & 1u);   // RNE
    return (unsigned short)(u >> 16);
}
__device__ __forceinline__ float softplus_f(float x) {
    if (x > 20.f) return x;
    return __logf(1.f + __expf(x));
}
// de = softplus(dtv), e1 = exp(-de) == 1/(1+exp(dtv)) (identity; rcp(inf)=0 handles overflow)
__device__ __forceinline__ void softplus_e1(float dtv, float& de, float& e1) {
    float E = __expf(dtv);
    de = (dtv > 20.f) ? dtv : __logf(1.f + E);
    e1 = __builtin_amdgcn_rcpf(1.f + E);
}
// scan-order index t -> image position (row-major h*64+w)
__device__ __forceinline__ int posk(int k, int t) {
    int q = (k >= 2) ? (LL - 1 - t) : t;
    return (k & 1) ? (((q & 63) << 6) | (q >> 6)) : q;
}
__device__ __forceinline__ float dot8(const float wr[8], const float* __restrict__ rec) {
    float4 q0 = *(const float4*)rec;
    float4 q1 = *(const float4*)(rec + 4);
    return wr[0] * q0.x + wr[1] * q0.y + wr[2] * q0.z + wr[3] * q0.w
         + wr[4] * q1.x + wr[5] * q1.y + wr[6] * q1.z + wr[7] * q1.w;
}
__device__ __forceinline__ void load_wr(const float* __restrict__ dtw, int kd, float wr[8]) {
    float4 v0 = *(const float4*)(dtw + (size_t)kd * 8);
    float4 v1 = *(const float4*)(dtw + (size_t)kd * 8 + 4);
    wr[0] = v0.x; wr[1] = v0.y; wr[2] = v0.z; wr[3] = v0.w;
    wr[4] = v1.x; wr[5] = v1.y; wr[6] = v1.z; wr[7] = v1.w;
}
// true iff -exp(A_logs[kd][n]) == -(n+1)  (A_logs = log(1..16) structure)
__device__ __forceinline__ bool check_chain(const float* __restrict__ A_logs, int kd) {
    float a0 = -__expf(A_logs[(size_t)kd * 16]);
    bool ok = fabsf(a0 + 1.f) < 1e-6f;
    #pragma unroll
    for (int n = 1; n < 16; ++n) {
        float an = -__expf(A_logs[(size_t)kd * 16 + n]);
        ok = ok && (fabsf(an - (float)(n + 1) * a0) <= 1e-4f * fabsf(an));
    }
    return ok;
}

// ---------- kernel 1: in_proj GEMM via MFMA bf16 ----------
// out[row][d] = sum_c x[row][c]*W[d][c], M=16384 N=256 K=128
__global__ __launch_bounds__(256) void k_inproj(const float* __restrict__ x,
                                                const float* __restrict__ wp,
                                                float* __restrict__ out) {
    __shared__ short sA[64][40];
    __shared__ short sW[256][40];
    int r0 = blockIdx.x * 64;
    int tid = threadIdx.x;
    int w = tid >> 6, lane = tid & 63;
    int ln15 = lane & 15, q8 = (lane >> 4) * 8;
    f32x4 acc[16];
    #pragma unroll
    for (int i = 0; i < 16; ++i) acc[i] = f32x4{0.f, 0.f, 0.f, 0.f};
    for (int kk = 0; kk < 4; ++kk) {
        {
            int r = tid >> 2, c0 = (tid & 3) * 8;
            const float* src = x + (size_t)(r0 + r) * DM + kk * 32 + c0;
            float4 v0 = *(const float4*)src;
            float4 v1 = *(const float4*)(src + 4);
            bf16x8 s;
            s[0] = (short)f2bf(v0.x); s[1] = (short)f2bf(v0.y);
            s[2] = (short)f2bf(v0.z); s[3] = (short)f2bf(v0.w);
            s[4] = (short)f2bf(v1.x); s[5] = (short)f2bf(v1.y);
            s[6] = (short)f2bf(v1.z); s[7] = (short)f2bf(v1.w);
            *(bf16x8*)&sA[r][c0] = s;
        }
        {
            const float* src = wp + (size_t)tid * DM + kk * 32;
            #pragma unroll
            for (int j = 0; j < 8; ++j) {
                float4 v = *(const float4*)(src + j * 4);
                sW[tid][j * 4 + 0] = (short)f2bf(v.x);
                sW[tid][j * 4 + 1] = (short)f2bf(v.y);
                sW[tid][j * 4 + 2] = (short)f2bf(v.z);
                sW[tid][j * 4 + 3] = (short)f2bf(v.w);
            }
        }
        __syncthreads();
        bf16x8 a = *(bf16x8*)&sA[w * 16 + ln15][q8];
        #pragma unroll
        for (int ni = 0; ni < 16; ++ni) {
            bf16x8 bfr = *(bf16x8*)&sW[ni * 16 + ln15][q8];
            acc[ni] = __builtin_amdgcn_mfma_f32_16x16x32_bf16(a, bfr, acc[ni], 0, 0, 0);
        }
        __syncthreads();
    }
    int rbase = r0 + w * 16 + (lane >> 4) * 4;
    #pragma unroll
    for (int ni = 0; ni < 16; ++ni)
        #pragma unroll
        for (int r = 0; r < 4; ++r)
            out[(size_t)(rbase + r) * DI + ni * 16 + ln15] = acc[ni][r];
}

// ---------- kernel 2: depthwise 3x3 conv + bias + SiLU, channel-last; emits bf16 only ----------
__global__ __launch_bounds__(256) void k_conv(const float* __restrict__ xin,
                                              const float* __restrict__ cw,
                                              const float* __restrict__ cb,
                                              unsigned short* __restrict__ xoutB) {
    int bid = blockIdx.x;
    int hh   = bid & 1;
    int wblk = (bid >> 1) & 15;
    int dblk = (bid >> 5) & 3;
    int b    = bid >> 7;
    int tid = threadIdx.x;
    int d = dblk * 64 + (tid & 63);
    int w = wblk * 4 + (tid >> 6);
    const float* inb = xin + (size_t)b * LL * DI + d;
    unsigned short* outbB = xoutB + (size_t)b * LL * DI + d;
    float wg[9];
    #pragma unroll
    for (int i = 0; i < 9; ++i) wg[i] = cw[d * 9 + i];
    float bias = cb[d];
    #define LDV(hhh, www) ((((www) >= 0) && ((www) < Wn)) ? inb[(size_t)((hhh) * Wn + (www)) * DI] : 0.f)
    int hs = hh * 32;
    float r0[3], r1[3], r2[3];
    if (hs == 0) { r0[0] = r0[1] = r0[2] = 0.f; }
    else { r0[0] = LDV(hs - 1, w - 1); r0[1] = LDV(hs - 1, w); r0[2] = LDV(hs - 1, w + 1); }
    r1[0] = LDV(hs, w - 1); r1[1] = LDV(hs, w); r1[2] = LDV(hs, w + 1);
    r2[0] = LDV(hs + 1, w - 1); r2[1] = LDV(hs + 1, w); r2[2] = LDV(hs + 1, w + 1);
    for (int h = hs; h < hs + 32; ++h) {
        float acc = bias + wg[0] * r0[0] + wg[1] * r0[1] + wg[2] * r0[2]
                         + wg[3] * r1[0] + wg[4] * r1[1] + wg[5] * r1[2]
                         + wg[6] * r2[0] + wg[7] * r2[1] + wg[8] * r2[2];
        float sig = 1.f / (1.f + __expf(-acc));
        outbB[(size_t)(h * Wn + w) * DI] = f2bf(acc * sig);
        r0[0] = r1[0]; r0[1] = r1[1]; r0[2] = r1[2];
        r1[0] = r2[0]; r1[1] = r2[1]; r1[2] = r2[2];
        if (h + 2 < Hn) { r2[0] = LDV(h + 2, w - 1); r2[1] = LDV(h + 2, w); r2[2] = LDV(h + 2, w + 1); }
        else { r2[0] = r2[1] = r2[2] = 0.f; }
    }
    #undef LDV
}

// ---------- kernel 3: projection GEMM via MFMA bf16 ----------
// P[row][c] = sum_d xpw[c][d]*xcB[row][d], M=16384 N=160 K=256
__global__ __launch_bounds__(256) void k_proj(const unsigned short* __restrict__ xcB,
                                              const float* __restrict__ xpw,
                                              float* __restrict__ P) {
    __shared__ short sA[64][40];
    __shared__ short sW[160][40];
    int r0 = blockIdx.x * 64;
    int tid = threadIdx.x;
    int w = tid >> 6, lane = tid & 63;
    int ln15 = lane & 15, q8 = (lane >> 4) * 8;
    f32x4 acc[10];
    #pragma unroll
    for (int i = 0; i < 10; ++i) acc[i] = f32x4{0.f, 0.f, 0.f, 0.f};
    for (int kk = 0; kk < 8; ++kk) {
        {
            int r = tid >> 2, c0 = (tid & 3) * 8;
            *(bf16x8*)&sA[r][c0] =
                *(const bf16x8*)(xcB + (size_t)(r0 + r) * DI + kk * 32 + c0);
        }
        if (tid < 160) {
            const float* src = xpw + (size_t)tid * DI + kk * 32;
            #pragma unroll
            for (int j = 0; j < 8; ++j) {
                float4 v = *(const float4*)(src + j * 4);
                sW[tid][j * 4 + 0] = (short)f2bf(v.x);
                sW[tid][j * 4 + 1] = (short)f2bf(v.y);
                sW[tid][j * 4 + 2] = (short)f2bf(v.z);
                sW[tid][j * 4 + 3] = (short)f2bf(v.w);
            }
        }
        __syncthreads();
        bf16x8 a = *(bf16x8*)&sA[w * 16 + ln15][q8];
        #pragma unroll
        for (int ni = 0; ni < 10; ++ni) {
            bf16x8 bfr = *(bf16x8*)&sW[ni * 16 + ln15][q8];
            acc[ni] = __builtin_amdgcn_mfma_f32_16x16x32_bf16(a, bfr, acc[ni], 0, 0, 0);
        }
        __syncthreads();
    }
    int rbase = r0 + w * 16 + (lane >> 4) * 4;
    #pragma unroll
    for (int ni = 0; ni < 10; ++ni)
        #pragma unroll
        for (int r = 0; r < 4; ++r)
            P[(size_t)(rbase + r) * 160 + ni * 16 + ln15] = acc[ni][r];
}

// ---------- scan step helpers ----------
// local scan step: updates h (local recurrence), sde; returns y_local = D*u + sum h*C
template <bool CHAIN>
__device__ __forceinline__ float s1_step(const float* __restrict__ rec, const float wr[8],
                                         float bias, float u, float Dv,
                                         const float* __restrict__ A_logs, int kd,
                                         float h[16], float& sde) {
    float dtv = bias + dot8(wr, rec);
    float de, e1;
    softplus_e1(dtv, de, e1);
    float du = de * u;
    sde += de;
    float Ba[16], Ca[16];
    #pragma unroll
    for (int i = 0; i < 4; ++i) {
        float4 v = *(const float4*)(rec + 8 + i * 4);
        Ba[i * 4 + 0] = v.x; Ba[i * 4 + 1] = v.y; Ba[i * 4 + 2] = v.z; Ba[i * 4 + 3] = v.w;
        float4 w = *(const float4*)(rec + 24 + i * 4);
        Ca[i * 4 + 0] = w.x; Ca[i * 4 + 1] = w.y; Ca[i * 4 + 2] = w.z; Ca[i * 4 + 3] = w.w;
    }
    float yv = Dv * u;
    if constexpr (CHAIN) {
        float en = e1;
        #pragma unroll
        for (int n = 0; n < 16; ++n) {
            h[n] = en * h[n] + du * Ba[n];
            yv += h[n] * Ca[n];
            en *= e1;
        }
    } else {
        #pragma unroll
        for (int n = 0; n < 16; ++n) {
            float Ac = -__expf(A_logs[(size_t)kd * 16 + n]);
            h[n] = __expf(de * Ac) * h[n] + du * Ba[n];
            yv += h[n] * Ca[n];
        }
    }
    return yv;
}
// correction step: pe = running prod of e1 (== exp(-cumde)); returns C . diag(pe^(n+1)) . h0
template <bool CHAIN>
__device__ __forceinline__ float s3_step(const float* __restrict__ rec, const float wr[8],
                                         float bias, const float* __restrict__ A_logs, int kd,
                                         const float h0[16], float& pe, float& sde) {
    float dtv = bias + dot8(wr, rec);
    float Ca[16];
    #pragma unroll
    for (int i = 0; i < 4; ++i) {
        float4 w = *(const float4*)(rec + 24 + i * 4);
        Ca[i * 4 + 0] = w.x; Ca[i * 4 + 1] = w.y; Ca[i * 4 + 2] = w.z; Ca[i * 4 + 3] = w.w;
    }
    float corr = 0.f;
    if constexpr (CHAIN) {
        float E = __expf(dtv);
        float e1 = __builtin_amdgcn_rcpf(1.f + E);
        pe *= e1;
        float pw = pe;
        #pragma unroll
        for (int n = 0; n < 16; ++n) {
            corr += Ca[n] * pw * h0[n];
            pw *= pe;
        }
    } else {
        float de = softplus_f(dtv);
        sde += de;
        #pragma unroll
        for (int n = 0; n < 16; ++n) {
            float Ac = -__expf(A_logs[(size_t)kd * 16 + n]);
            corr += Ca[n] * __expf(Ac * sde) * h0[n];
        }
    }
    return corr;
}

// ---------- kernel 4: paired local scan — y_local plain stores + carries ----------
// grid 1024 = 4b * 2pair * 128c ; pair0 = dirs {0,2} -> y0(=d_out), pair1 = {1,3} -> y1 (scan-order layout)
__global__ __launch_bounds__(256, 4) void k_scan1p(const unsigned short* __restrict__ xcB,
                                                   const float* __restrict__ P,
                                                   const float* __restrict__ dtw,
                                                   const float* __restrict__ dtb,
                                                   const float* __restrict__ A_logs,
                                                   const float* __restrict__ Ds,
                                                   float* __restrict__ carrG,
                                                   unsigned short* __restrict__ carrH,
                                                   float* __restrict__ y0,
                                                   float* __restrict__ y1) {
    __shared__ float sY[CHUNK * 256];   // per-thread column accumulators (no cross-thread use)
    int bid = blockIdx.x;
    int c = bid & (NC - 1);
    int p = (bid >> 7) & 1;
    int b = bid >> 8;
    int tid = threadIdx.x;
    int kA = p, kB = p + 2, cB = NC - 1 - c;
    int kdA = kA * DI + tid, kdB = kB * DI + tid;
    float wrA[8], wrB[8];
    load_wr(dtw, kdA, wrA);
    load_wr(dtw, kdB, wrB);
    float biasA = dtb[kdA], biasB = dtb[kdB];
    float DvA = Ds[kdA], DvB = Ds[kdB];
    bool ch = check_chain(A_logs, kdA) && check_chain(A_logs, kdB);
    float hA[16], hB[16];
    #pragma unroll
    for (int n = 0; n < 16; ++n) { hA[n] = 0.f; hB[n] = 0.f; }
    float sdeA = 0.f, sdeB = 0.f;
    for (int j = 0; j < CHUNK; ++j) sY[j * 256 + tid] = 0.f;
    const unsigned short* xb = xcB + (size_t)b * LL * DI;
    const float* PbA = P + (size_t)b * LL * 160 + kA * 40;
    const float* PbB = P + (size_t)b * LL * 160 + kB * 40;
    int t0A = c * CHUNK, t0B = cB * CHUNK;
    if (ch) {
        for (int tt = 0; tt < CHUNK; ++tt) {
            int posA = posk(kA, t0A + tt);
            float uA = bf2f(xb[(size_t)posA * DI + tid]);
            float yvA = s1_step<true>(PbA + (size_t)posA * 160, wrA, biasA, uA, DvA, A_logs, kdA, hA, sdeA);
            sY[tt * 256 + tid] += yvA;
            int posB = posk(kB, t0B + tt);
            float uB = bf2f(xb[(size_t)posB * DI + tid]);
            float yvB = s1_step<true>(PbB + (size_t)posB * 160, wrB, biasB, uB, DvB, A_logs, kdB, hB, sdeB);
            sY[(CHUNK - 1 - tt) * 256 + tid] += yvB;
        }
    } else {
        for (int tt = 0; tt < CHUNK; ++tt) {
            int posA = posk(kA, t0A + tt);
            float uA = bf2f(xb[(size_t)posA * DI + tid]);
            float yvA = s1_step<false>(PbA + (size_t)posA * 160, wrA, biasA, uA, DvA, A_logs, kdA, hA, sdeA);
            sY[tt * 256 + tid] += yvA;
            int posB = posk(kB, t0B + tt);
            float uB = bf2f(xb[(size_t)posB * DI + tid]);
            float yvB = s1_step<false>(PbB + (size_t)posB * 160, wrB, biasB, uB, DvB, A_logs, kdB, hB, sdeB);
            sY[(CHUNK - 1 - tt) * 256 + tid] += yvB;
        }
    }
    // carries
    carrG[((size_t)(b * Kn + kA) * NC + c) * DI + tid] = sdeA;
    carrG[((size_t)(b * Kn + kB) * NC + cB) * DI + tid] = sdeB;
    size_t hbA = ((size_t)(b * Kn + kA) * NC + c) * 16 * DI + tid;
    size_t hbB = ((size_t)(b * Kn + kB) * NC + cB) * 16 * DI + tid;
    #pragma unroll
    for (int n = 0; n < 16; ++n) {
        carrH[hbA + (size_t)n * DI] = f2bf(hA[n]);
        carrH[hbB + (size_t)n * DI] = f2bf(hB[n]);
    }
    // plain stores of the shared 32-position window (owner-exclusive)
    float* yb = (p == 0 ? y0 : y1) + ((size_t)b * LL + c * CHUNK) * DI + tid;
    for (int j = 0; j < CHUNK; ++j)
        yb[(size_t)j * DI] = sY[j * 256 + tid];
}

// ---------- kernel 5: scan phase 2 — combine carries across chunks ----------
// grid 256 ; block 256 ; thread = (bk,n,d); a_c recomputed as exp(Ac*sde_c)
__global__ __launch_bounds__(256) void k_scan2(const float* __restrict__ carrG,
                                               const float* __restrict__ A_logs,
                                               unsigned short* __restrict__ carrH) {
    int gid = blockIdx.x * 256 + threadIdx.x;
    int d = gid & 255;
    int n = (gid >> 8) & 15;
    int bk = gid >> 12;
    int k = bk & 3;
    float Ac = -__expf(A_logs[(size_t)(k * DI + d) * 16 + n]);
    size_t gbase = (size_t)bk * NC * DI + d;
    size_t hbase = ((size_t)bk * NC * 16 + n) * DI + d;
    const size_t hs = (size_t)16 * DI;
    float hr = 0.f;
    #pragma unroll
    for (int g = 0; g < NC / 32; ++g) {
        float sv[32];
        unsigned short hvv[32];
        #pragma unroll
        for (int j = 0; j < 32; ++j) sv[j] = carrG[gbase + (size_t)(g * 32 + j) * DI];
        #pragma unroll
        for (int j = 0; j < 32; ++j) hvv[j] = carrH[hbase + (size_t)(g * 32 + j) * hs];
        #pragma unroll
        for (int j = 0; j < 32; ++j) {
            float a = __expf(Ac * sv[j]);
            float he = bf2f(hvv[j]);
            carrH[hbase + (size_t)(g * 32 + j) * hs] = f2bf(hr);   // h_init for this chunk
            hr = a * hr + he;
        }
    }
}

// ---------- kernel 6: paired correction — y += C . pe^(n+1) . h_init ----------
// grid 1024 ; owner-exclusive RMW of the same windows as k_scan1p
__global__ __launch_bounds__(256, 4) void k_scan3p(const float* __restrict__ P,
                                                   const float* __restrict__ dtw,
                                                   const float* __restrict__ dtb,
                                                   const float* __restrict__ A_logs,
                                                   const unsigned short* __restrict__ carrH,
                                                   float* __restrict__ y0,
                                                   float* __restrict__ y1) {
    __shared__ float sY[CHUNK * 256];
    int bid = blockIdx.x;
    int c = bid & (NC - 1);
    int p = (bid >> 7) & 1;
    int b = bid >> 8;
    int tid = threadIdx.x;
    int kA = p, kB = p + 2, cB = NC - 1 - c;
    int kdA = kA * DI + tid, kdB = kB * DI + tid;
    float wrA[8], wrB[8];
    load_wr(dtw, kdA, wrA);
    load_wr(dtw, kdB, wrB);
    float biasA = dtb[kdA], biasB = dtb[kdB];
    bool ch = check_chain(A_logs, kdA) && check_chain(A_logs, kdB);
    float h0A[16], h0B[16];
    size_t hbA = ((size_t)(b * Kn + kA) * NC + c) * 16 * DI + tid;
    size_t hbB = ((size_t)(b * Kn + kB) * NC + cB) * 16 * DI + tid;
    #pragma unroll
    for (int n = 0; n < 16; ++n) {
        h0A[n] = bf2f(carrH[hbA + (size_t)n * DI]);
        h0B[n] = bf2f(carrH[hbB + (size_t)n * DI]);
    }
    for (int j = 0; j < CHUNK; ++j) sY[j * 256 + tid] = 0.f;
    const float* PbA = P + (size_t)b * LL * 160 + kA * 40;
    const float* PbB = P + (size_t)b * LL * 160 + kB * 40;
    int t0A = c * CHUNK, t0B = cB * CHUNK;
    float peA = 1.f, peB = 1.f, sdeA = 0.f, sdeB = 0.f;
    if (ch) {
        for (int tt = 0; tt < CHUNK; ++tt) {
            int posA = posk(kA, t0A + tt);
            sY[tt * 256 + tid] += s3_step<true>(PbA + (size_t)posA * 160, wrA, biasA, A_logs, kdA, h0A, peA, sdeA);
            int posB = posk(kB, t0B + tt);
            sY[(CHUNK - 1 - tt) * 256 + tid] += s3_step<true>(PbB + (size_t)posB * 160, wrB, biasB, A_logs, kdB, h0B, peB, sdeB);
        }
    } else {
        for (int tt = 0; tt < CHUNK; ++tt) {
            int posA = posk(kA, t0A + tt);
            sY[tt * 256 + tid] += s3_step<false>(PbA + (size_t)posA * 160, wrA, biasA, A_logs, kdA, h0A, peA, sdeA);
            int posB = posk(kB, t0B + tt);
            sY[(CHUNK - 1 - tt) * 256 + tid] += s3_step<false>(PbB + (size_t)posB * 160, wrB, biasB, A_logs, kdB, h0B, peB, sdeB);
        }
    }
    float* yb = (p == 0 ? y0 : y1) + ((size_t)b * LL + c * CHUNK) * DI + tid;
    for (int j = 0; j < CHUNK; ++j)
        yb[(size_t)j * DI] += sY[j * 256 + tid];
}

// ---------- kernel 7: LayerNorm over last dim: y0 (in-place) + transposed y1 ----------
// grid 16384 rows ; block 256
__global__ __launch_bounds__(256) void k_ln(float* __restrict__ y,
                                            const float* __restrict__ y1,
                                            const float* __restrict__ gamma,
                                            const float* __restrict__ beta) {
    __shared__ float s1[4], s2[4];
    int r = blockIdx.x;
    int tid = threadIdx.x;
    int b = r >> 12;
    int pos = r & 4095;
    int q = ((pos & 63) << 6) | (pos >> 6);   // y1 is stored in wh-scan order
    float v = y[(size_t)r * DI + tid] + y1[((size_t)b * LL + q) * DI + tid];
    float a = v, bsq = v * v;
    #pragma unroll
    for (int off = 32; off; off >>= 1) {
        a += __shfl_xor(a, off);
        bsq += __shfl_xor(bsq, off);
    }
    if ((tid & 63) == 0) { s1[tid >> 6] = a; s2[tid >> 6] = bsq; }
    __syncthreads();
    float S1 = s1[0] + s1[1] + s1[2] + s1[3];
    float S2 = s2[0] + s2[1] + s2[2] + s2[3];
    float mu = S1 * (1.f / 256.f);
    float var = S2 * (1.f / 256.f) - mu * mu;
    float rs = rsqrtf(var + 1e-5f);
    y[(size_t)r * DI + tid] = (v - mu) * rs * gamma[tid] + beta[tid];
}

// ---------- launch ----------
extern "C" void kernel_launch(void* const* d_in, const int* in_sizes, int n_in,
                              void* d_out, int out_size, void* d_ws, size_t ws_size,
                              hipStream_t stream) {
    const float* x    = (const float*)d_in[0];
    const float* ipw  = (const float*)d_in[1];
    const float* cw   = (const float*)d_in[2];
    const float* cb   = (const float*)d_in[3];
    const float* xpw  = (const float*)d_in[4];
    const float* dtw  = (const float*)d_in[5];
    const float* dtb  = (const float*)d_in[6];
    const float* alog = (const float*)d_in[7];
    const float* Ds   = (const float*)d_in[8];
    const float* gam  = (const float*)d_in[9];
    const float* bet  = (const float*)d_in[10];

    // ws layout (bytes):
    //   [0, 16777216)           carrH (bf16 B*K*NC*16*DI)  -- aliases xls_pre (in_proj out, dead after conv)
    //   [16777216, 18874368)    carrG (fp32 B*K*NC*DI)
    //   [18874368, 27262976)    xcB   (bf16 B*L*DI, conv+SiLU output, channel-last)
    //   [27262976, 37748736)    P     (fp32 B*L*160 projection records, image order: [k*40: dts|B|C])
    //   [37748736, 54525952)    y1    (fp32 B*L*DI, pair{1,3} partial in wh-scan order)
    //   y0 lives in d_out (pair{0,2} partial, then LN in-place)
    const size_t WS_NEED = 54525952;
    if (ws_size < WS_NEED) return;

    char* ws = (char*)d_ws;
    unsigned short* carrH = (unsigned short*)(ws + 0);
    float* carrG   = (float*)(ws + 16777216);
    float* xls_pre = (float*)(ws + 0);           // alias over carrH (dead before scan1p)
    unsigned short* xcB = (unsigned short*)(ws + 18874368);
    float* P       = (float*)(ws + 27262976);
    float* y1      = (float*)(ws + 37748736);
    float* y       = (float*)d_out;

    k_inproj<<<256,   256, 0, stream>>>(x, ipw, xls_pre);
    k_conv  <<<512,   256, 0, stream>>>(xls_pre, cw, cb, xcB);
    k_proj  <<<256,   256, 0, stream>>>(xcB, xpw, P);
    k_scan1p<<<1024,  256, 0, stream>>>(xcB, P, dtw, dtb, alog, Ds, carrG, carrH, y, y1);
    k_scan2 <<<256,   256, 0, stream>>>(carrG, alog, carrH);
    k_scan3p<<<1024,  256, 0, stream>>>(P, dtw, dtb, alog, carrH, y, y1);
    k_ln    <<<16384, 256, 0, stream>>>(y, y1, gam, bet);
}